// Round 10
// baseline (8346.880 us; speedup 1.0000x reference)
//
#include <hip/hip_runtime.h>
#include <stdint.h>

typedef unsigned int u32;
typedef unsigned short u16;
typedef unsigned char u8;
typedef long long i64;
typedef __attribute__((ext_vector_type(4))) float f32x4;
typedef __attribute__((ext_vector_type(4))) float f32x4v;
typedef __attribute__((ext_vector_type(8))) short bf16x8;

#define T_LEN 100
#define S_LEN 400
#define NB 16
#define HD 512
#define CTXD 1024
#define VOC 50000
#define K4H 2048
#define M_ALL 1600

static __device__ __forceinline__ float bf2f(u16 v) {
  union { u32 u; float f; } c; c.u = ((u32)v) << 16; return c.f;
}
static __device__ __forceinline__ u16 f2bf(float f) {
  union { float f; u32 u; } c; c.f = f;
  return (u16)((c.u + 0x7fffu + ((c.u >> 16) & 1u)) >> 16);
}
static __device__ __forceinline__ u32 pack2(float a, float b) {
  return (u32)f2bf(a) | ((u32)f2bf(b) << 16);
}
static __device__ __forceinline__ uint4 pack8(float4 a, float4 b) {
  return make_uint4(pack2(a.x, a.y), pack2(a.z, a.w), pack2(b.x, b.y), pack2(b.z, b.w));
}
static __device__ __forceinline__ uint4 pack8v(f32x4v a, f32x4v b) {
  return make_uint4(pack2(a.x, a.y), pack2(a.z, a.w), pack2(b.x, b.y), pack2(b.z, b.w));
}
static __device__ __forceinline__ u32 pkfp8(float x, float y, float z, float w) {
  int p = 0;
  p = __builtin_amdgcn_cvt_pk_fp8_f32(x, y, p, 0);
  p = __builtin_amdgcn_cvt_pk_fp8_f32(z, w, p, 1);
  return (u32)p;
}
static __device__ __forceinline__ float sigm(float x) { return 1.f / (1.f + __expf(-x)); }
static __device__ __forceinline__ float tanh_(float x) {
  float e = __expf(2.f * x);
  return 1.f - 2.f / (e + 1.f);
}
// coherent (agent-scope, L2-bypassing) scalar load/store — no fences needed
static __device__ __forceinline__ float ald(const float* p) {
  return __hip_atomic_load(p, __ATOMIC_RELAXED, __HIP_MEMORY_SCOPE_AGENT);
}
static __device__ __forceinline__ void ast(float* p, float v) {
  __hip_atomic_store(p, v, __ATOMIC_RELAXED, __HIP_MEMORY_SCOPE_AGENT);
}

__global__ void sentinel_kernel(float* out, float v) {
  if (threadIdx.x < NB) out[threadIdx.x] = v;
}

// ---------------- fused cast kernel ----------------
struct CastArgs {
  const float* src[9];
  u16* dst[9];
  u32 cum[10];
};

__global__ __launch_bounds__(256) void cast_all(CastArgs A) {
  u32 i = blockIdx.x * 256 + threadIdx.x;
  if (i >= A.cum[9]) return;
  int seg = 0;
  while (i >= A.cum[seg + 1]) seg++;
  u32 li = i - A.cum[seg];
  const float* s = A.src[seg];
  f32x4v a = __builtin_nontemporal_load((const f32x4v*)&s[li * 8]);
  f32x4v b = __builtin_nontemporal_load((const f32x4v*)&s[li * 8 + 4]);
  if (seg < 8) {
    *(uint4*)&A.dst[seg][li * 8] = pack8v(a, b);
  } else {  // y_emb -> feat8[:, 1536:2048] (fp8)
    u32 m = li >> 6, k8 = (li & 63) << 3;
    u8* f8 = (u8*)A.dst[8];
    uint2 t;
    t.x = pkfp8(a.x, a.y, a.z, a.w);
    t.y = pkfp8(b.x, b.y, b.z, b.w);
    *(uint2*)&f8[(size_t)m * K4H + 1536 + k8] = t;
  }
}

// ---------------- generic bf16 MFMA GEMM ----------------
template <int MODE>
__global__ __launch_bounds__(256) void gemm_bf16(const u16* __restrict__ A,
                                                 const u16* __restrict__ Bw,
                                                 void* __restrict__ out,
                                                 const float* __restrict__ bias1,
                                                 const float* __restrict__ bias2,
                                                 int M, int N, int K) {
  __shared__ u16 As[64][40];
  __shared__ u16 Bs[64][40];
  int nb = N / 64;
  int m0 = (blockIdx.x / nb) * 64;
  int n0 = (blockIdx.x % nb) * 64;
  int tid = threadIdx.x;
  int lane = tid & 63;
  int w = tid >> 6;
  int wm = (w >> 1) * 32, wn = (w & 1) * 32;
  f32x4 acc[2][2] = {};
  int arow = tid >> 2, achk = (tid & 3) * 8;
  for (int k0 = 0; k0 < K; k0 += 32) {
    __syncthreads();
    *(uint4*)&As[arow][achk] = *(const uint4*)&A[(size_t)(m0 + arow) * K + k0 + achk];
    *(uint4*)&Bs[arow][achk] = *(const uint4*)&Bw[(size_t)(n0 + arow) * K + k0 + achk];
    __syncthreads();
    int r = lane & 15, kg = lane >> 4;
    bf16x8 a0 = *(const bf16x8*)&As[wm + r][kg * 8];
    bf16x8 a1 = *(const bf16x8*)&As[wm + 16 + r][kg * 8];
    bf16x8 b0 = *(const bf16x8*)&Bs[wn + r][kg * 8];
    bf16x8 b1 = *(const bf16x8*)&Bs[wn + 16 + r][kg * 8];
    acc[0][0] = __builtin_amdgcn_mfma_f32_16x16x32_bf16(a0, b0, acc[0][0], 0, 0, 0);
    acc[0][1] = __builtin_amdgcn_mfma_f32_16x16x32_bf16(a0, b1, acc[0][1], 0, 0, 0);
    acc[1][0] = __builtin_amdgcn_mfma_f32_16x16x32_bf16(a1, b0, acc[1][0], 0, 0, 0);
    acc[1][1] = __builtin_amdgcn_mfma_f32_16x16x32_bf16(a1, b1, acc[1][1], 0, 0, 0);
  }
  int col = lane & 15, rg = lane >> 4;
#pragma unroll
  for (int fi = 0; fi < 2; fi++)
#pragma unroll
    for (int fj = 0; fj < 2; fj++)
#pragma unroll
      for (int r = 0; r < 4; r++) {
        int m = m0 + wm + fi * 16 + rg * 4 + r;
        int n = n0 + wn + fj * 16 + col;
        float v = acc[fi][fj][r] + bias1[n];
        if constexpr (MODE == 1) {
          v += bias2[n];
          ((float*)out)[(size_t)m * N + n] = v;
        } else {
          ((u16*)out)[(size_t)m * N + n] = f2bf(v);
        }
      }
}

// ---------------- persistent decoder: LDS-resident attention + fence-free barrier ----------------
struct DecArgs {
  const u16 *pctx, *ctx, *Whh, *Wcomb, *Uxw, *Wxw;
  const float *xW, *bx, *uatt, *xmask, *ymask, *init_h, *init_c;
  float *h, *c, *h1, *c1, *qsum, *attnum, *attden;
  u8* feat8;
  u32* bar;
};

// Fence-free grid barrier. All cross-barrier data moves via agent-scope
// atomics (coherent at IF, bypassing stale L2), so no wbl2/inv needed.
// bar layout (u32 idx): [0] root count; [64+g*64] group flag (256B apart);
// [1088+g*64] group count.
static __device__ __forceinline__ void gbar(u32* bar, u32 gen) {
  __syncthreads();
  if (threadIdx.x == 0) {
    asm volatile("s_waitcnt vmcnt(0) lgkmcnt(0)" ::: "memory");
    const int g = blockIdx.x >> 4;
    u32* gcnt = bar + 1088 + g * 64;
    u32* gflag = bar + 64 + g * 64;
    u32 old = __hip_atomic_fetch_add(gcnt, 1u, __ATOMIC_RELAXED, __HIP_MEMORY_SCOPE_AGENT);
    if (old == gen * 16u - 1u) {
      u32 r = __hip_atomic_fetch_add(bar, 1u, __ATOMIC_RELAXED, __HIP_MEMORY_SCOPE_AGENT);
      if (r == gen * 16u - 1u) {
        for (int i = 0; i < 16; i++)
          __hip_atomic_store(bar + 64 + i * 64, gen, __ATOMIC_RELAXED,
                             __HIP_MEMORY_SCOPE_AGENT);
      }
    }
    while (__hip_atomic_load(gflag, __ATOMIC_RELAXED, __HIP_MEMORY_SCOPE_AGENT) < gen)
      __builtin_amdgcn_s_sleep(4);
    asm volatile("" ::: "memory");
  }
  __syncthreads();
}

// Dynamic LDS (bytes), total 160,448:
//   [0,      51200)  pctx_l  u16[25*1024]     (persistent)
//   [51200, 102400)  ctx_l   u16[25*1024]     (persistent)
//   [102400,106752)  ua_lp   f32[1088] padded (persistent)
//   [106752,106880)  xm_l    f32[32]          (persistent)
//   [106880,160448)  phase union:
//     A: Al u16[16*520] @0 | gbA f32[4][16][32] @16640 | h1c1 u16[16*72] @24832
//     C: q_lp f32[1088] @0 | p_l f32[32] @4352
//     D: AlD u16[16*1544] @0 | gbD f32[4][16][16] @49408 | attden_l f32[16] @53504
__global__ __launch_bounds__(256, 1) void decoder_coop(DecArgs A) {
  extern __shared__ char smem[];
  u16* pctx_l = (u16*)smem;
  u16* ctx_l = (u16*)(smem + 51200);
  float* ua_lp = (float*)(smem + 102400);
  float* xm_l = (float*)(smem + 106752);
  char* un = smem + 106880;

  const int tid = threadIdx.x;
  const int blk = blockIdx.x;
  const int lane = tid & 63, w = tid >> 6;
  const int r16 = lane & 15, kg = lane >> 4;
  const int bK = blk & 15;
  const int s0 = (blk >> 4) * 25;
  u32 gen = 1;

  // ---- one-time prefill of persistent LDS ----
  for (int idx = tid; idx < 25 * 128; idx += 256) {
    int i = idx >> 7, c8 = (idx & 127) << 3;
    *(uint4*)&pctx_l[i * 1024 + c8] =
        *(const uint4*)&A.pctx[((size_t)(s0 + i) * NB + bK) * CTXD + c8];
    *(uint4*)&ctx_l[i * 1024 + c8] =
        *(const uint4*)&A.ctx[((size_t)(s0 + i) * NB + bK) * CTXD + c8];
  }
  {
    int c0 = tid * 4;
    int p = (c0 >> 4) * 17 + (c0 & 15);
#pragma unroll
    for (int j = 0; j < 4; j++) ua_lp[p + j] = A.uatt[c0 + j];
  }
  if (tid < 25) xm_l[tid] = A.xmask[(s0 + tid) * NB + bK];

  for (int ts = 0; ts < T_LEN; ts++) {
    const int par = ts & 1;
    // ========= phase A: LSTM1 + q partials -> qsum (blocks 0..15) =========
    if (blk < 16) {
      u16* Al = (u16*)un;
      float* gbA = (float*)(un + 16640);
      u16* h1c1 = (u16*)(un + 24832);
      const float* hs = ts ? A.h : A.init_h;
      const float* cs = ts ? A.c : A.init_c;
#pragma unroll
      for (int i = 0; i < 32; i++) {
        int idx = i * 256 + tid;
        int b = idx >> 9, k = idx & 511;
        Al[b * 520 + k] = f2bf(ald(&hs[b * 512 + k]));
      }
      __syncthreads();
      const int j0 = blk * 32;
      {
        f32x4 acc0 = {}, acc1 = {};
        const size_t row0 = (size_t)(w * 512 + j0 + r16) * 512;
        const size_t row1 = (size_t)(w * 512 + j0 + 16 + r16) * 512;
#pragma unroll
        for (int ks = 0; ks < 16; ks++) {
          bf16x8 a = *(const bf16x8*)&Al[r16 * 520 + ks * 32 + kg * 8];
          bf16x8 b0 = *(const bf16x8*)&A.Whh[row0 + ks * 32 + kg * 8];
          bf16x8 b1 = *(const bf16x8*)&A.Whh[row1 + ks * 32 + kg * 8];
          acc0 = __builtin_amdgcn_mfma_f32_16x16x32_bf16(a, b0, acc0, 0, 0, 0);
          acc1 = __builtin_amdgcn_mfma_f32_16x16x32_bf16(a, b1, acc1, 0, 0, 0);
        }
#pragma unroll
        for (int r = 0; r < 4; r++) {
          gbA[(w * 16 + kg * 4 + r) * 32 + r16] = acc0[r];
          gbA[(w * 16 + kg * 4 + r) * 32 + 16 + r16] = acc1[r];
        }
      }
      __syncthreads();
#pragma unroll
      for (int i = 0; i < 2; i++) {
        int idx = i * 256 + tid;
        int b = idx >> 5, j = idx & 31;
        int n = j0 + j;
        const float* xw = &A.xW[(size_t)(ts * NB + b) * K4H];
        float gi = gbA[(0 * 16 + b) * 32 + j] + xw[n];
        float gf = gbA[(1 * 16 + b) * 32 + j] + xw[512 + n];
        float gg = gbA[(2 * 16 + b) * 32 + j] + xw[1024 + n];
        float go = gbA[(3 * 16 + b) * 32 + j] + xw[1536 + n];
        float ymv = A.ymask[ts * NB + b];
        float c_old = ald(&cs[b * 512 + n]);
        float h_old = ald(&hs[b * 512 + n]);
        float c1v = sigm(gf) * c_old + sigm(gi) * tanh_(gg);
        float h1v = sigm(go) * tanh_(c1v);
        h1v = ymv * h1v + (1.f - ymv) * h_old;
        c1v = ymv * c1v + (1.f - ymv) * c_old;
        ast(&A.h1[b * 512 + n], h1v);
        ast(&A.c1[b * 512 + n], c1v);
        h1c1[b * 72 + j] = f2bf(h1v);
        h1c1[b * 72 + 32 + j] = f2bf(c1v);
      }
      __syncthreads();
      {
        bf16x8 a0 = *(const bf16x8*)&h1c1[r16 * 72 + kg * 8];
        bf16x8 a1 = *(const bf16x8*)&h1c1[r16 * 72 + 32 + kg * 8];
        float* qs = A.qsum + par * 16384;
        for (int nt = w; nt < 64; nt += 4) {
          int n = nt * 16 + r16;
          bf16x8 b0 = *(const bf16x8*)&A.Wcomb[(size_t)n * 1024 + j0 + kg * 8];
          bf16x8 b1 = *(const bf16x8*)&A.Wcomb[(size_t)n * 1024 + 512 + j0 + kg * 8];
          f32x4 acc = {};
          acc = __builtin_amdgcn_mfma_f32_16x16x32_bf16(a0, b0, acc, 0, 0, 0);
          acc = __builtin_amdgcn_mfma_f32_16x16x32_bf16(a1, b1, acc, 0, 0, 0);
#pragma unroll
          for (int r = 0; r < 4; r++)
            atomicAdd(&qs[(kg * 4 + r) * 1024 + nt * 16 + r16], acc[r]);
        }
      }
    }
    gbar(A.bar, gen); gen++;
    // ========= phase C: attention (all 256 blocks; LDS-resident operands) =========
    {
      float* q_lp = (float*)un;
      float* p_l = (float*)(un + 4352);
      {
        int c0 = tid * 4;
        const float* qs = &A.qsum[par * 16384 + bK * 1024 + c0];
        int p = (c0 >> 4) * 17 + (c0 & 15);
#pragma unroll
        for (int j = 0; j < 4; j++) q_lp[p + j] = ald(qs + j);
      }
      __syncthreads();
      for (int i = w; i < 25; i += 4) {
        const u16* prow = &pctx_l[i * 1024 + lane * 16];
        float s = 0.f;
#pragma unroll
        for (int half = 0; half < 2; half++) {
          bf16x8 pv = *(const bf16x8*)&prow[half * 8];
#pragma unroll
          for (int e = 0; e < 8; e++) {
            int cc = lane * 17 + half * 8 + e;
            s += tanh_(bf2f((u16)pv[e]) + q_lp[cc]) * ua_lp[cc];
          }
        }
#pragma unroll
        for (int off = 1; off < 64; off <<= 1) s += __shfl_xor(s, off);
        if (lane == 0) {
          float xm = xm_l[i];
          p_l[i] = __expf(s * xm) * xm;
        }
      }
      __syncthreads();
      const int c4 = tid << 2;
      float n0 = 0, n1 = 0, n2 = 0, n3 = 0;
#pragma unroll 5
      for (int i = 0; i < 25; i++) {
        float pv = p_l[i];
        uint2 ld = *(const uint2*)&ctx_l[i * 1024 + c4];
        n0 += pv * bf2f((u16)(ld.x & 0xffff));
        n1 += pv * bf2f((u16)(ld.x >> 16));
        n2 += pv * bf2f((u16)(ld.y & 0xffff));
        n3 += pv * bf2f((u16)(ld.y >> 16));
      }
      float* dst = &A.attnum[par * 16384 + bK * 1024 + c4];
      atomicAdd(dst + 0, n0);
      atomicAdd(dst + 1, n1);
      atomicAdd(dst + 2, n2);
      atomicAdd(dst + 3, n3);
      if (tid == 0) {
        float d = 0.f;
        for (int i = 0; i < 25; i++) d += p_l[i];
        atomicAdd(&A.attden[par * NB + bK], d);
      }
    }
    gbar(A.bar, gen); gen++;
    // ========= phase D: gates2 + state update (blocks 0..31) =========
    if (blk < 32) {
      u16* AlD = (u16*)un;
      float* gbD = (float*)(un + 49408);
      float* attden_l = (float*)(un + 53504);
      if (tid < NB) attden_l[tid] = ald(&A.attden[par * NB + tid]);
#pragma unroll
      for (int i = 0; i < 32; i++) {
        int idx = i * 256 + tid;
        int b = idx >> 9, k = idx & 511;
        AlD[b * 1544 + k] = f2bf(ald(&A.h1[b * 512 + k]));
      }
      __syncthreads();
#pragma unroll
      for (int i = 0; i < 64; i++) {
        int idx = i * 256 + tid;
        int b = idx >> 10, cc = idx & 1023;
        float av = ald(&A.attnum[par * 16384 + b * 1024 + cc]) / attden_l[b];
        AlD[b * 1544 + 512 + cc] = f2bf(av);
      }
      __syncthreads();
      if (blk < 16) {
        const u16* arow = &AlD[blk * 1544 + 512];
        int c4 = tid * 4;
        u32 p = pkfp8(bf2f(arow[c4]), bf2f(arow[c4 + 1]), bf2f(arow[c4 + 2]),
                      bf2f(arow[c4 + 3]));
        *(u32*)&A.feat8[(size_t)(ts * NB + blk) * K4H + 512 + c4] = p;
      }
      const int j0 = blk * 16;
      f32x4 acc = {};
      const size_t rowU = (size_t)(w * 512 + j0 + r16) * 512;
      const size_t rowW = (size_t)(w * 512 + j0 + r16) * 1024;
#pragma unroll
      for (int ks = 0; ks < 16; ks++) {
        bf16x8 a = *(const bf16x8*)&AlD[r16 * 1544 + ks * 32 + kg * 8];
        bf16x8 b0 = *(const bf16x8*)&A.Uxw[rowU + ks * 32 + kg * 8];
        acc = __builtin_amdgcn_mfma_f32_16x16x32_bf16(a, b0, acc, 0, 0, 0);
      }
#pragma unroll
      for (int ks = 16; ks < 48; ks++) {
        bf16x8 a = *(const bf16x8*)&AlD[r16 * 1544 + ks * 32 + kg * 8];
        bf16x8 b0 = *(const bf16x8*)&A.Wxw[rowW + (ks - 16) * 32 + kg * 8];
        acc = __builtin_amdgcn_mfma_f32_16x16x32_bf16(a, b0, acc, 0, 0, 0);
      }
#pragma unroll
      for (int r = 0; r < 4; r++) gbD[(w * 16 + kg * 4 + r) * 16 + r16] = acc[r];
      __syncthreads();
      {
        int b = tid >> 4, j = tid & 15;
        int n = j0 + j;
        float xi = gbD[(0 * 16 + b) * 16 + j] + A.bx[n];
        float xf = gbD[(1 * 16 + b) * 16 + j] + A.bx[512 + n];
        float xo = gbD[(2 * 16 + b) * 16 + j] + A.bx[1024 + n];
        float xc = gbD[(3 * 16 + b) * 16 + j] + A.bx[1536 + n];
        float ymv = A.ymask[ts * NB + b];
        float c1v = ald(&A.c1[b * 512 + n]);
        float h1v = ald(&A.h1[b * 512 + n]);
        float c2 = sigm(xf) * c1v + sigm(xi) * tanh_(xc);
        float h2 = sigm(xo) * tanh_(c2);
        c2 = ymv * c2 + (1.f - ymv) * c1v;
        h2 = ymv * h2 + (1.f - ymv) * h1v;
        ast(&A.h[b * 512 + n], h2);
        ast(&A.c[b * 512 + n], c2);
        int p8 = 0;
        p8 = __builtin_amdgcn_cvt_pk_fp8_f32(h2, h2, p8, 0);
        A.feat8[(size_t)(ts * NB + b) * K4H + n] = (u8)(p8 & 0xff);
      }
      // zero other-parity attnum/attden + current-parity qsum for future steps
      ast(&A.attnum[(par ^ 1) * 16384 + blk * 512 + tid], 0.f);
      ast(&A.attnum[(par ^ 1) * 16384 + blk * 512 + 256 + tid], 0.f);
      ast(&A.qsum[par * 16384 + blk * 512 + tid], 0.f);
      ast(&A.qsum[par * 16384 + blk * 512 + 256 + tid], 0.f);
      if (blk == 0 && tid < NB) ast(&A.attden[(par ^ 1) * NB + tid], 0.f);
    }
    gbar(A.bar, gen); gen++;
  }
}

// ---------------- fused vocab GEMM (fp8) + sum(exp) ----------------
__global__ __launch_bounds__(512, 1) void lse_gemm_fp8(const u8* __restrict__ feat8,
                                                       const float* __restrict__ Wp,
                                                       const float* __restrict__ bp,
                                                       float* __restrict__ lse) {
  extern __shared__ char smem[];
  u8* Bl = (u8*)smem;  // [64][2064] fp8
  const int tid = threadIdx.x;
  const int n0 = blockIdx.x * 64;
  for (int n = 0; n < 64; n++) {
    int gn = n0 + n;
    f32x4v f = {0.f, 0.f, 0.f, 0.f};
    if (gn < VOC)
      f = __builtin_nontemporal_load((const f32x4v*)&Wp[(size_t)gn * K4H + tid * 4]);
    *(u32*)&Bl[n * 2064 + tid * 4] = pkfp8(f.x, f.y, f.z, f.w);
  }
  __syncthreads();
  const int w = tid >> 6, lane = tid & 63;
  const int r16 = lane & 15, kg = lane >> 4;
  bool vj[4];
  float bpj[4];
#pragma unroll
  for (int j = 0; j < 4; j++) {
    int nf = n0 + j * 16 + r16;
    vj[j] = nf < VOC;
    bpj[j] = vj[j] ? bp[nf] : 0.f;
  }
  for (int qq = w; qq < 25; qq += 8) {
    int mrow = qq * 64;
    f32x4 acc[4][4] = {};
    for (int ks = 0; ks < 64; ks++) {
      i64 b0 = *(const i64*)&Bl[(r16) * 2064 + ks * 32 + kg * 8];
      i64 b1 = *(const i64*)&Bl[(16 + r16) * 2064 + ks * 32 + kg * 8];
      i64 b2 = *(const i64*)&Bl[(32 + r16) * 2064 + ks * 32 + kg * 8];
      i64 b3 = *(const i64*)&Bl[(48 + r16) * 2064 + ks * 32 + kg * 8];
#pragma unroll
      for (int s = 0; s < 4; s++) {
        i64 a = *(const i64*)&feat8[(size_t)(mrow + s * 16 + r16) * K4H + ks * 32 + kg * 8];
        acc[s][0] = __builtin_amdgcn_mfma_f32_16x16x32_fp8_fp8(a, b0, acc[s][0], 0, 0, 0);
        acc[s][1] = __builtin_amdgcn_mfma_f32_16x16x32_fp8_fp8(a, b1, acc[s][1], 0, 0, 0);
        acc[s][2] = __builtin_amdgcn_mfma_f32_16x16x32_fp8_fp8(a, b2, acc[s][2], 0, 0, 0);
        acc[s][3] = __builtin_amdgcn_mfma_f32_16x16x32_fp8_fp8(a, b3, acc[s][3], 0, 0, 0);
      }
    }
#pragma unroll
    for (int s = 0; s < 4; s++) {
#pragma unroll
      for (int r = 0; r < 4; r++) {
        float e = 0.f;
#pragma unroll
        for (int j = 0; j < 4; j++)
          if (vj[j]) e += __expf(acc[s][j][r] + bpj[j]);
        e += __shfl_xor(e, 1);
        e += __shfl_xor(e, 2);
        e += __shfl_xor(e, 4);
        e += __shfl_xor(e, 8);
        if (r16 == 0) atomicAdd(&lse[mrow + s * 16 + kg * 4 + r], e);
      }
    }
  }
}

// ---------------- target logit ----------------
__global__ __launch_bounds__(256) void target_logit(const u8* __restrict__ feat8,
                                                    const float* __restrict__ Wp,
                                                    const float* __restrict__ bp,
                                                    const int* __restrict__ yidx,
                                                    float* __restrict__ tlog) {
  int gw = (blockIdx.x * 256 + threadIdx.x) >> 6;
  int lane = threadIdx.x & 63;
  if (gw >= M_ALL) return;
  int yi = yidx[gw];
  const float* wrow = Wp + (size_t)yi * K4H;
  const u8* frow = feat8 + (size_t)gw * K4H;
  float s = 0.f;
#pragma unroll
  for (int i = 0; i < 4; i++) {
    int k = i * 512 + lane * 8;
    uint2 fv = *(const uint2*)&frow[k];
    f32x4v w0 = __builtin_nontemporal_load((const f32x4v*)&wrow[k]);
    f32x4v w1 = __builtin_nontemporal_load((const f32x4v*)&wrow[k + 4]);
    s += __builtin_amdgcn_cvt_f32_fp8(fv.x, 0) * w0.x;
    s += __builtin_amdgcn_cvt_f32_fp8(fv.x, 1) * w0.y;
    s += __builtin_amdgcn_cvt_f32_fp8(fv.x, 2) * w0.z;
    s += __builtin_amdgcn_cvt_f32_fp8(fv.x, 3) * w0.w;
    s += __builtin_amdgcn_cvt_f32_fp8(fv.y, 0) * w1.x;
    s += __builtin_amdgcn_cvt_f32_fp8(fv.y, 1) * w1.y;
    s += __builtin_amdgcn_cvt_f32_fp8(fv.y, 2) * w1.z;
    s += __builtin_amdgcn_cvt_f32_fp8(fv.y, 3) * w1.w;
  }
#pragma unroll
  for (int off = 1; off < 64; off <<= 1) s += __shfl_xor(s, off);
  if (lane == 0) tlog[gw] = s + bp[yi];
}

__global__ void finalize(const float* __restrict__ lse, const float* __restrict__ tlog,
                         const float* __restrict__ ymask, float* __restrict__ out) {
  int b = threadIdx.x;
  if (b < NB) {
    float sc = 0.f, sm = 0.f;
    for (int t = 0; t < T_LEN; t++) {
      int m = t * NB + b;
      float ym = ymask[m];
      sc += (logf(lse[m]) - tlog[m]) * ym;
      sm += ym;
    }
    out[b] = sc / sm;
  }
}

// ---------------- host launcher ----------------
extern "C" void kernel_launch(void* const* d_in, const int* in_sizes, int n_in,
                              void* d_out, int out_size, void* d_ws, size_t ws_size,
                              hipStream_t stream) {
  const float* y_emb = (const float*)d_in[0];
  const float* context = (const float*)d_in[1];
  const float* init_h = (const float*)d_in[2];
  const float* init_c = (const float*)d_in[3];
  const float* x_mask = (const float*)d_in[4];
  const float* y_mask = (const float*)d_in[5];
  const int* y_idx = (const int*)d_in[6];
  const float* W_ih = (const float*)d_in[7];
  const float* W_hh = (const float*)d_in[8];
  const float* b_ih = (const float*)d_in[9];
  const float* b_hh = (const float*)d_in[10];
  const float* Wx = (const float*)d_in[11];
  const float* Ux = (const float*)d_in[12];
  const float* bx = (const float*)d_in[13];
  const float* Wc_att = (const float*)d_in[14];
  const float* b_att = (const float*)d_in[15];
  const float* W_comb = (const float*)d_in[16];
  const float* U_att = (const float*)d_in[17];
  const float* Wp = (const float*)d_in[18];
  const float* bp = (const float*)d_in[19];

  if (ws_size < 60000000ULL) {
    sentinel_kernel<<<1, 64, 0, stream>>>((float*)d_out, (float)(ws_size >> 20));
    return;
  }

  // ---- workspace layout: ALL OFFSETS/SIZES IN BYTES (end 59,342,848) ----
  char* ws = (char*)d_ws;
  float* lse = (float*)(ws + 0);              // 6,400 B (zeroed)
  float* attnum = (float*)(ws + 8192);        // 131,072 B (zeroed)
  float* attden = (float*)(ws + 139264);      // 128 B (zeroed)
  u32* bar = (u32*)(ws + 139392);             // 12,288 B (zeroed)
  float* qsum = (float*)(ws + 151680);        // 131,072 B (zeroed)
  float* tlog = (float*)(ws + 282752);        // 6,400 B
  u16* pctx = (u16*)(ws + 294912);            // 13,107,200 B
  u16* ctxb = (u16*)(ws + 13402112);          // 13,107,200 B
  u16* Wcb = (u16*)(ws + 26509312);           // 2,097,152 B
  u16* yembb = (u16*)(ws + 28606464);         // 1,638,400 B (prologue only)
  u16* Wihb = (u16*)(ws + 30244864);          // 2,097,152 B
  u16* Whhb = (u16*)(ws + 32342016);          // 2,097,152 B
  u16* Wcombb = (u16*)(ws + 34439168);        // 2,097,152 B
  u16* Uxb = (u16*)(ws + 36536320);           // 2,097,152 B
  u16* Wxb = (u16*)(ws + 38633472);           // 4,194,304 B
  float* xW = (float*)(ws + 42827776);        // 13,107,200 B
  u8* feat8 = (u8*)(ws + 55934976);           // 3,276,800 B
  float* hbuf = (float*)(ws + 59211776);      // 32,768 B
  float* cbuf = (float*)(ws + 59244544);      // 32,768 B
  float* h1buf = (float*)(ws + 59277312);     // 32,768 B
  float* c1buf = (float*)(ws + 59310080);     // 32,768 B

  hipMemsetAsync(ws, 0, 282752, stream);  // lse+attnum+attden+bar+qsum

  CastArgs ca;
  ca.src[0] = context;  ca.dst[0] = ctxb;
  ca.src[1] = Wc_att;   ca.dst[1] = Wcb;
  ca.src[2] = y_emb;    ca.dst[2] = yembb;
  ca.src[3] = W_ih;     ca.dst[3] = Wihb;
  ca.src[4] = W_hh;     ca.dst[4] = Whhb;
  ca.src[5] = W_comb;   ca.dst[5] = Wcombb;
  ca.src[6] = Ux;       ca.dst[6] = Uxb;
  ca.src[7] = Wx;       ca.dst[7] = Wxb;
  ca.src[8] = y_emb;    ca.dst[8] = (u16*)feat8;
  u32 sz[9] = {819200, 131072, 102400, 131072, 131072, 131072, 131072, 262144, 102400};
  ca.cum[0] = 0;
  for (int i = 0; i < 9; i++) ca.cum[i + 1] = ca.cum[i] + sz[i];
  cast_all<<<(ca.cum[9] + 255) / 256, 256, 0, stream>>>(ca);

  gemm_bf16<0><<<1600, 256, 0, stream>>>(ctxb, Wcb, pctx, b_att, b_att, 6400, 1024, 1024);
  gemm_bf16<1><<<800, 256, 0, stream>>>(yembb, Wihb, xW, b_ih, b_hh, 1600, 2048, 512);

  DecArgs a;
  a.pctx = pctx; a.ctx = ctxb; a.Whh = Whhb; a.Wcomb = Wcombb; a.Uxw = Uxb; a.Wxw = Wxb;
  a.xW = xW; a.bx = bx; a.uatt = U_att; a.xmask = x_mask; a.ymask = y_mask;
  a.init_h = init_h; a.init_c = init_c;
  a.h = hbuf; a.c = cbuf; a.h1 = h1buf; a.c1 = c1buf; a.qsum = qsum;
  a.attnum = attnum; a.attden = attden; a.feat8 = feat8; a.bar = bar;
  hipFuncSetAttribute(reinterpret_cast<const void*>(decoder_coop),
                      hipFuncAttributeMaxDynamicSharedMemorySize, 160448);
  decoder_coop<<<256, 256, 160448, stream>>>(a);

  hipFuncSetAttribute(reinterpret_cast<const void*>(lse_gemm_fp8),
                      hipFuncAttributeMaxDynamicSharedMemorySize, 132096);
  lse_gemm_fp8<<<782, 512, 132096, stream>>>(feat8, Wp, bp, lse);

  target_logit<<<400, 256, 0, stream>>>(feat8, Wp, bp, y_idx, tlog);
  finalize<<<1, 64, 0, stream>>>(lse, tlog, y_mask, (float*)d_out);
}

// Round 11
// 5136.298 us; speedup vs baseline: 1.6251x; 1.6251x over previous
//
#include <hip/hip_runtime.h>
#include <stdint.h>

typedef unsigned int u32;
typedef unsigned short u16;
typedef unsigned char u8;
typedef long long i64;
typedef __attribute__((ext_vector_type(4))) float f32x4;
typedef __attribute__((ext_vector_type(4))) float f32x4v;
typedef __attribute__((ext_vector_type(8))) short bf16x8;

#define T_LEN 100
#define S_LEN 400
#define NB 16
#define HD 512
#define CTXD 1024
#define VOC 50000
#define K4H 2048
#define M_ALL 1600

static __device__ __forceinline__ float bf2f(u16 v) {
  union { u32 u; float f; } c; c.u = ((u32)v) << 16; return c.f;
}
static __device__ __forceinline__ u16 f2bf(float f) {
  union { float f; u32 u; } c; c.f = f;
  return (u16)((c.u + 0x7fffu + ((c.u >> 16) & 1u)) >> 16);
}
static __device__ __forceinline__ u32 pack2(float a, float b) {
  return (u32)f2bf(a) | ((u32)f2bf(b) << 16);
}
static __device__ __forceinline__ uint4 pack8(float4 a, float4 b) {
  return make_uint4(pack2(a.x, a.y), pack2(a.z, a.w), pack2(b.x, b.y), pack2(b.z, b.w));
}
static __device__ __forceinline__ uint4 pack8v(f32x4v a, f32x4v b) {
  return make_uint4(pack2(a.x, a.y), pack2(a.z, a.w), pack2(b.x, b.y), pack2(b.z, b.w));
}
static __device__ __forceinline__ u32 pkfp8(float x, float y, float z, float w) {
  int p = 0;
  p = __builtin_amdgcn_cvt_pk_fp8_f32(x, y, p, 0);
  p = __builtin_amdgcn_cvt_pk_fp8_f32(z, w, p, 1);
  return (u32)p;
}
static __device__ __forceinline__ float sigm(float x) { return 1.f / (1.f + __expf(-x)); }
static __device__ __forceinline__ float tanh_(float x) {
  float e = __expf(2.f * x);
  return 1.f - 2.f / (e + 1.f);
}
// coherent scalar load/store (agent scope; bypasses stale L2)
static __device__ __forceinline__ float ald(const float* p) {
  return __hip_atomic_load(p, __ATOMIC_RELAXED, __HIP_MEMORY_SCOPE_AGENT);
}
static __device__ __forceinline__ void ast(float* p, float v) {
  __hip_atomic_store(p, v, __ATOMIC_RELAXED, __HIP_MEMORY_SCOPE_AGENT);
}
// coherent 16B load, single (waits internally)
static __device__ __forceinline__ f32x4v cld4(const float* p) {
  f32x4v v;
  asm volatile("global_load_dwordx4 %0, %1, off sc0 sc1\n\t"
               "s_waitcnt vmcnt(0)"
               : "=&v"(v) : "v"(p) : "memory");
  return v;
}
// coherent 16B loads, batch of 8 with one waitcnt (hides latency)
static __device__ __forceinline__ void cld8(
    const float* p0, const float* p1, const float* p2, const float* p3,
    const float* p4, const float* p5, const float* p6, const float* p7,
    f32x4v& v0, f32x4v& v1, f32x4v& v2, f32x4v& v3,
    f32x4v& v4, f32x4v& v5, f32x4v& v6, f32x4v& v7) {
  asm volatile(
      "global_load_dwordx4 %0, %8, off sc0 sc1\n\t"
      "global_load_dwordx4 %1, %9, off sc0 sc1\n\t"
      "global_load_dwordx4 %2, %10, off sc0 sc1\n\t"
      "global_load_dwordx4 %3, %11, off sc0 sc1\n\t"
      "global_load_dwordx4 %4, %12, off sc0 sc1\n\t"
      "global_load_dwordx4 %5, %13, off sc0 sc1\n\t"
      "global_load_dwordx4 %6, %14, off sc0 sc1\n\t"
      "global_load_dwordx4 %7, %15, off sc0 sc1\n\t"
      "s_waitcnt vmcnt(0)"
      : "=&v"(v0), "=&v"(v1), "=&v"(v2), "=&v"(v3),
        "=&v"(v4), "=&v"(v5), "=&v"(v6), "=&v"(v7)
      : "v"(p0), "v"(p1), "v"(p2), "v"(p3), "v"(p4), "v"(p5), "v"(p6), "v"(p7)
      : "memory");
}

__global__ void sentinel_kernel(float* out, float v) {
  if (threadIdx.x < NB) out[threadIdx.x] = v;
}

// ---------------- fused cast kernel ----------------
struct CastArgs {
  const float* src[9];
  u16* dst[9];
  u32 cum[10];
};

__global__ __launch_bounds__(256) void cast_all(CastArgs A) {
  u32 i = blockIdx.x * 256 + threadIdx.x;
  if (i >= A.cum[9]) return;
  int seg = 0;
  while (i >= A.cum[seg + 1]) seg++;
  u32 li = i - A.cum[seg];
  const float* s = A.src[seg];
  f32x4v a = __builtin_nontemporal_load((const f32x4v*)&s[li * 8]);
  f32x4v b = __builtin_nontemporal_load((const f32x4v*)&s[li * 8 + 4]);
  if (seg < 8) {
    *(uint4*)&A.dst[seg][li * 8] = pack8v(a, b);
  } else {  // y_emb -> feat8[:, 1536:2048] (fp8)
    u32 m = li >> 6, k8 = (li & 63) << 3;
    u8* f8 = (u8*)A.dst[8];
    uint2 t;
    t.x = pkfp8(a.x, a.y, a.z, a.w);
    t.y = pkfp8(b.x, b.y, b.z, b.w);
    *(uint2*)&f8[(size_t)m * K4H + 1536 + k8] = t;
  }
}

// ---------------- generic bf16 MFMA GEMM ----------------
template <int MODE>
__global__ __launch_bounds__(256) void gemm_bf16(const u16* __restrict__ A,
                                                 const u16* __restrict__ Bw,
                                                 void* __restrict__ out,
                                                 const float* __restrict__ bias1,
                                                 const float* __restrict__ bias2,
                                                 int M, int N, int K) {
  __shared__ u16 As[64][40];
  __shared__ u16 Bs[64][40];
  int nb = N / 64;
  int m0 = (blockIdx.x / nb) * 64;
  int n0 = (blockIdx.x % nb) * 64;
  int tid = threadIdx.x;
  int lane = tid & 63;
  int w = tid >> 6;
  int wm = (w >> 1) * 32, wn = (w & 1) * 32;
  f32x4 acc[2][2] = {};
  int arow = tid >> 2, achk = (tid & 3) * 8;
  for (int k0 = 0; k0 < K; k0 += 32) {
    __syncthreads();
    *(uint4*)&As[arow][achk] = *(const uint4*)&A[(size_t)(m0 + arow) * K + k0 + achk];
    *(uint4*)&Bs[arow][achk] = *(const uint4*)&Bw[(size_t)(n0 + arow) * K + k0 + achk];
    __syncthreads();
    int r = lane & 15, kg = lane >> 4;
    bf16x8 a0 = *(const bf16x8*)&As[wm + r][kg * 8];
    bf16x8 a1 = *(const bf16x8*)&As[wm + 16 + r][kg * 8];
    bf16x8 b0 = *(const bf16x8*)&Bs[wn + r][kg * 8];
    bf16x8 b1 = *(const bf16x8*)&Bs[wn + 16 + r][kg * 8];
    acc[0][0] = __builtin_amdgcn_mfma_f32_16x16x32_bf16(a0, b0, acc[0][0], 0, 0, 0);
    acc[0][1] = __builtin_amdgcn_mfma_f32_16x16x32_bf16(a0, b1, acc[0][1], 0, 0, 0);
    acc[1][0] = __builtin_amdgcn_mfma_f32_16x16x32_bf16(a1, b0, acc[1][0], 0, 0, 0);
    acc[1][1] = __builtin_amdgcn_mfma_f32_16x16x32_bf16(a1, b1, acc[1][1], 0, 0, 0);
  }
  int col = lane & 15, rg = lane >> 4;
#pragma unroll
  for (int fi = 0; fi < 2; fi++)
#pragma unroll
    for (int fj = 0; fj < 2; fj++)
#pragma unroll
      for (int r = 0; r < 4; r++) {
        int m = m0 + wm + fi * 16 + rg * 4 + r;
        int n = n0 + wn + fj * 16 + col;
        float v = acc[fi][fj][r] + bias1[n];
        if constexpr (MODE == 1) {
          v += bias2[n];
          ((float*)out)[(size_t)m * N + n] = v;
        } else {
          ((u16*)out)[(size_t)m * N + n] = f2bf(v);
        }
      }
}

// ---------------- persistent decoder ----------------
struct DecArgs {
  const u16 *pctx, *ctx, *Whh, *Wcomb, *Uxw, *Wxw;
  const float *xW, *bx, *uatt, *xmask, *ymask, *init_h, *init_c;
  float *h, *c, *h1, *c1, *qsum, *attnum, *attden;
  u8* feat8;
  u32* bar;
};

// Fence-free grid barrier (cross-barrier data moves via coherent ops).
static __device__ __forceinline__ void gbar(u32* bar, u32 gen) {
  __syncthreads();
  if (threadIdx.x == 0) {
    asm volatile("s_waitcnt vmcnt(0) lgkmcnt(0)" ::: "memory");
    const int g = blockIdx.x >> 4;
    u32* gcnt = bar + 1088 + g * 64;
    u32* gflag = bar + 64 + g * 64;
    u32 old = __hip_atomic_fetch_add(gcnt, 1u, __ATOMIC_RELAXED, __HIP_MEMORY_SCOPE_AGENT);
    if (old == gen * 16u - 1u) {
      u32 r = __hip_atomic_fetch_add(bar, 1u, __ATOMIC_RELAXED, __HIP_MEMORY_SCOPE_AGENT);
      if (r == gen * 16u - 1u) {
        for (int i = 0; i < 16; i++)
          __hip_atomic_store(bar + 64 + i * 64, gen, __ATOMIC_RELAXED,
                             __HIP_MEMORY_SCOPE_AGENT);
      }
    }
    while (__hip_atomic_load(gflag, __ATOMIC_RELAXED, __HIP_MEMORY_SCOPE_AGENT) < gen)
      __builtin_amdgcn_s_sleep(4);
    asm volatile("" ::: "memory");
  }
  __syncthreads();
}

// Dynamic LDS (bytes), total 160,448 — see round-10 layout comment.
__global__ __launch_bounds__(256, 1) void decoder_coop(DecArgs A) {
  extern __shared__ char smem[];
  u16* pctx_l = (u16*)smem;
  u16* ctx_l = (u16*)(smem + 51200);
  float* ua_lp = (float*)(smem + 102400);
  float* xm_l = (float*)(smem + 106752);
  char* un = smem + 106880;

  const int tid = threadIdx.x;
  const int blk = blockIdx.x;
  const int lane = tid & 63, w = tid >> 6;
  const int r16 = lane & 15, kg = lane >> 4;
  const int bK = blk & 15;
  const int s0 = (blk >> 4) * 25;
  u32 gen = 1;

  // ---- one-time prefill of persistent LDS ----
  for (int idx = tid; idx < 25 * 128; idx += 256) {
    int i = idx >> 7, c8 = (idx & 127) << 3;
    *(uint4*)&pctx_l[i * 1024 + c8] =
        *(const uint4*)&A.pctx[((size_t)(s0 + i) * NB + bK) * CTXD + c8];
    *(uint4*)&ctx_l[i * 1024 + c8] =
        *(const uint4*)&A.ctx[((size_t)(s0 + i) * NB + bK) * CTXD + c8];
  }
  {
    int c0 = tid * 4;
    int p = (c0 >> 4) * 17 + (c0 & 15);
#pragma unroll
    for (int j = 0; j < 4; j++) ua_lp[p + j] = A.uatt[c0 + j];
  }
  if (tid < 25) xm_l[tid] = A.xmask[(s0 + tid) * NB + bK];

  for (int ts = 0; ts < T_LEN; ts++) {
    const int par = ts & 1;
    // ========= phase A: LSTM1 + q partials -> qsum (blocks 0..15) =========
    if (blk < 16) {
      u16* Al = (u16*)un;
      float* gbA = (float*)(un + 16640);
      u16* h1c1 = (u16*)(un + 24832);
      const float* hs = ts ? A.h : A.init_h;
      const float* cs = ts ? A.c : A.init_c;
      {
        const int b0_ = tid >> 6, k80 = (tid & 63) << 3;
        const int b1_ = (256 + tid) >> 6, k81 = ((256 + tid) & 63) << 3;
        const int b2_ = (512 + tid) >> 6, k82 = ((512 + tid) & 63) << 3;
        const int b3_ = (768 + tid) >> 6, k83 = ((768 + tid) & 63) << 3;
        f32x4v v0, v1, v2, v3, v4, v5, v6, v7;
        cld8(&hs[b0_ * 512 + k80], &hs[b0_ * 512 + k80 + 4],
             &hs[b1_ * 512 + k81], &hs[b1_ * 512 + k81 + 4],
             &hs[b2_ * 512 + k82], &hs[b2_ * 512 + k82 + 4],
             &hs[b3_ * 512 + k83], &hs[b3_ * 512 + k83 + 4],
             v0, v1, v2, v3, v4, v5, v6, v7);
        *(uint4*)&Al[b0_ * 520 + k80] = pack8v(v0, v1);
        *(uint4*)&Al[b1_ * 520 + k81] = pack8v(v2, v3);
        *(uint4*)&Al[b2_ * 520 + k82] = pack8v(v4, v5);
        *(uint4*)&Al[b3_ * 520 + k83] = pack8v(v6, v7);
      }
      __syncthreads();
      const int j0 = blk * 32;
      {
        f32x4 acc0 = {}, acc1 = {};
        const size_t row0 = (size_t)(w * 512 + j0 + r16) * 512;
        const size_t row1 = (size_t)(w * 512 + j0 + 16 + r16) * 512;
#pragma unroll
        for (int ks = 0; ks < 16; ks++) {
          bf16x8 a = *(const bf16x8*)&Al[r16 * 520 + ks * 32 + kg * 8];
          bf16x8 b0 = *(const bf16x8*)&A.Whh[row0 + ks * 32 + kg * 8];
          bf16x8 b1 = *(const bf16x8*)&A.Whh[row1 + ks * 32 + kg * 8];
          acc0 = __builtin_amdgcn_mfma_f32_16x16x32_bf16(a, b0, acc0, 0, 0, 0);
          acc1 = __builtin_amdgcn_mfma_f32_16x16x32_bf16(a, b1, acc1, 0, 0, 0);
        }
#pragma unroll
        for (int r = 0; r < 4; r++) {
          gbA[(w * 16 + kg * 4 + r) * 32 + r16] = acc0[r];
          gbA[(w * 16 + kg * 4 + r) * 32 + 16 + r16] = acc1[r];
        }
      }
      __syncthreads();
#pragma unroll
      for (int i = 0; i < 2; i++) {
        int idx = i * 256 + tid;
        int b = idx >> 5, j = idx & 31;
        int n = j0 + j;
        const float* xw = &A.xW[(size_t)(ts * NB + b) * K4H];
        float gi = gbA[(0 * 16 + b) * 32 + j] + xw[n];
        float gf = gbA[(1 * 16 + b) * 32 + j] + xw[512 + n];
        float gg = gbA[(2 * 16 + b) * 32 + j] + xw[1024 + n];
        float go = gbA[(3 * 16 + b) * 32 + j] + xw[1536 + n];
        float ymv = A.ymask[ts * NB + b];
        float c_old = ald(&cs[b * 512 + n]);
        float h_old = ald(&hs[b * 512 + n]);
        float c1v = sigm(gf) * c_old + sigm(gi) * tanh_(gg);
        float h1v = sigm(go) * tanh_(c1v);
        h1v = ymv * h1v + (1.f - ymv) * h_old;
        c1v = ymv * c1v + (1.f - ymv) * c_old;
        ast(&A.h1[b * 512 + n], h1v);
        ast(&A.c1[b * 512 + n], c1v);
        h1c1[b * 72 + j] = f2bf(h1v);
        h1c1[b * 72 + 32 + j] = f2bf(c1v);
      }
      __syncthreads();
      {
        bf16x8 a0 = *(const bf16x8*)&h1c1[r16 * 72 + kg * 8];
        bf16x8 a1 = *(const bf16x8*)&h1c1[r16 * 72 + 32 + kg * 8];
        float* qs = A.qsum + par * 16384;
        for (int nt = w; nt < 64; nt += 4) {
          int n = nt * 16 + r16;
          bf16x8 b0 = *(const bf16x8*)&A.Wcomb[(size_t)n * 1024 + j0 + kg * 8];
          bf16x8 b1 = *(const bf16x8*)&A.Wcomb[(size_t)n * 1024 + 512 + j0 + kg * 8];
          f32x4 acc = {};
          acc = __builtin_amdgcn_mfma_f32_16x16x32_bf16(a0, b0, acc, 0, 0, 0);
          acc = __builtin_amdgcn_mfma_f32_16x16x32_bf16(a1, b1, acc, 0, 0, 0);
#pragma unroll
          for (int r = 0; r < 4; r++)
            atomicAdd(&qs[(kg * 4 + r) * 1024 + nt * 16 + r16], acc[r]);
        }
      }
    }
    gbar(A.bar, gen); gen++;
    // ========= phase C: attention (all 256 blocks; LDS-resident operands) =========
    {
      float* q_lp = (float*)un;
      float* p_l = (float*)(un + 4352);
      {
        int c0 = tid * 4;
        f32x4v qv = cld4(&A.qsum[par * 16384 + bK * 1024 + c0]);
        int p = (c0 >> 4) * 17 + (c0 & 15);
        q_lp[p] = qv.x; q_lp[p + 1] = qv.y; q_lp[p + 2] = qv.z; q_lp[p + 3] = qv.w;
      }
      __syncthreads();
      for (int i = w; i < 25; i += 4) {
        const u16* prow = &pctx_l[i * 1024 + lane * 16];
        float s = 0.f;
#pragma unroll
        for (int half = 0; half < 2; half++) {
          bf16x8 pv = *(const bf16x8*)&prow[half * 8];
#pragma unroll
          for (int e = 0; e < 8; e++) {
            int cc = lane * 17 + half * 8 + e;
            s += tanh_(bf2f((u16)pv[e]) + q_lp[cc]) * ua_lp[cc];
          }
        }
#pragma unroll
        for (int off = 1; off < 64; off <<= 1) s += __shfl_xor(s, off);
        if (lane == 0) {
          float xm = xm_l[i];
          p_l[i] = __expf(s * xm) * xm;
        }
      }
      __syncthreads();
      const int c4 = tid << 2;
      float n0 = 0, n1 = 0, n2 = 0, n3 = 0;
#pragma unroll 5
      for (int i = 0; i < 25; i++) {
        float pv = p_l[i];
        uint2 ld = *(const uint2*)&ctx_l[i * 1024 + c4];
        n0 += pv * bf2f((u16)(ld.x & 0xffff));
        n1 += pv * bf2f((u16)(ld.x >> 16));
        n2 += pv * bf2f((u16)(ld.y & 0xffff));
        n3 += pv * bf2f((u16)(ld.y >> 16));
      }
      float* dst = &A.attnum[par * 16384 + bK * 1024 + c4];
      atomicAdd(dst + 0, n0);
      atomicAdd(dst + 1, n1);
      atomicAdd(dst + 2, n2);
      atomicAdd(dst + 3, n3);
      if (tid == 0) {
        float d = 0.f;
        for (int i = 0; i < 25; i++) d += p_l[i];
        atomicAdd(&A.attden[par * NB + bK], d);
      }
    }
    gbar(A.bar, gen); gen++;
    // ========= phase D: gates2 + state update (blocks 0..31) =========
    if (blk < 32) {
      u16* AlD = (u16*)un;
      float* gbD = (float*)(un + 49408);
      float* attden_l = (float*)(un + 53504);
      if (tid < NB) attden_l[tid] = ald(&A.attden[par * NB + tid]);
      {
        const int b0_ = tid >> 6, k80 = (tid & 63) << 3;
        const int b1_ = (256 + tid) >> 6, k81 = ((256 + tid) & 63) << 3;
        const int b2_ = (512 + tid) >> 6, k82 = ((512 + tid) & 63) << 3;
        const int b3_ = (768 + tid) >> 6, k83 = ((768 + tid) & 63) << 3;
        f32x4v v0, v1, v2, v3, v4, v5, v6, v7;
        cld8(&A.h1[b0_ * 512 + k80], &A.h1[b0_ * 512 + k80 + 4],
             &A.h1[b1_ * 512 + k81], &A.h1[b1_ * 512 + k81 + 4],
             &A.h1[b2_ * 512 + k82], &A.h1[b2_ * 512 + k82 + 4],
             &A.h1[b3_ * 512 + k83], &A.h1[b3_ * 512 + k83 + 4],
             v0, v1, v2, v3, v4, v5, v6, v7);
        *(uint4*)&AlD[b0_ * 1544 + k80] = pack8v(v0, v1);
        *(uint4*)&AlD[b1_ * 1544 + k81] = pack8v(v2, v3);
        *(uint4*)&AlD[b2_ * 1544 + k82] = pack8v(v4, v5);
        *(uint4*)&AlD[b3_ * 1544 + k83] = pack8v(v6, v7);
      }
      __syncthreads();
      // attnum staging: 16 coherent dwordx4 per thread (batch i -> att row i)
      {
        const float* base = &A.attnum[par * 16384];
        const int c4 = tid << 2;
        f32x4v a0, a1, a2, a3, a4, a5, a6, a7;
        cld8(base + 0 * 1024 + c4, base + 1 * 1024 + c4, base + 2 * 1024 + c4,
             base + 3 * 1024 + c4, base + 4 * 1024 + c4, base + 5 * 1024 + c4,
             base + 6 * 1024 + c4, base + 7 * 1024 + c4,
             a0, a1, a2, a3, a4, a5, a6, a7);
#define ATT_ST(i, vv)                                                        \
  {                                                                          \
    float rd = 1.f / attden_l[i];                                            \
    uint2 t;                                                                 \
    t.x = pack2(vv.x * rd, vv.y * rd);                                       \
    t.y = pack2(vv.z * rd, vv.w * rd);                                       \
    *(uint2*)&AlD[(i) * 1544 + 512 + c4] = t;                                \
  }
        ATT_ST(0, a0) ATT_ST(1, a1) ATT_ST(2, a2) ATT_ST(3, a3)
        ATT_ST(4, a4) ATT_ST(5, a5) ATT_ST(6, a6) ATT_ST(7, a7)
        cld8(base + 8 * 1024 + c4, base + 9 * 1024 + c4, base + 10 * 1024 + c4,
             base + 11 * 1024 + c4, base + 12 * 1024 + c4, base + 13 * 1024 + c4,
             base + 14 * 1024 + c4, base + 15 * 1024 + c4,
             a0, a1, a2, a3, a4, a5, a6, a7);
        ATT_ST(8, a0) ATT_ST(9, a1) ATT_ST(10, a2) ATT_ST(11, a3)
        ATT_ST(12, a4) ATT_ST(13, a5) ATT_ST(14, a6) ATT_ST(15, a7)
#undef ATT_ST
      }
      __syncthreads();
      if (blk < 16) {
        const u16* arow = &AlD[blk * 1544 + 512];
        int c4 = tid * 4;
        u32 p = pkfp8(bf2f(arow[c4]), bf2f(arow[c4 + 1]), bf2f(arow[c4 + 2]),
                      bf2f(arow[c4 + 3]));
        *(u32*)&A.feat8[(size_t)(ts * NB + blk) * K4H + 512 + c4] = p;
      }
      const int j0 = blk * 16;
      f32x4 acc = {};
      const size_t rowU = (size_t)(w * 512 + j0 + r16) * 512;
      const size_t rowW = (size_t)(w * 512 + j0 + r16) * 1024;
#pragma unroll
      for (int ks = 0; ks < 16; ks++) {
        bf16x8 a = *(const bf16x8*)&AlD[r16 * 1544 + ks * 32 + kg * 8];
        bf16x8 b0 = *(const bf16x8*)&A.Uxw[rowU + ks * 32 + kg * 8];
        acc = __builtin_amdgcn_mfma_f32_16x16x32_bf16(a, b0, acc, 0, 0, 0);
      }
#pragma unroll
      for (int ks = 16; ks < 48; ks++) {
        bf16x8 a = *(const bf16x8*)&AlD[r16 * 1544 + ks * 32 + kg * 8];
        bf16x8 b0 = *(const bf16x8*)&A.Wxw[rowW + (ks - 16) * 32 + kg * 8];
        acc = __builtin_amdgcn_mfma_f32_16x16x32_bf16(a, b0, acc, 0, 0, 0);
      }
#pragma unroll
      for (int r = 0; r < 4; r++) gbD[(w * 16 + kg * 4 + r) * 16 + r16] = acc[r];
      __syncthreads();
      {
        int b = tid >> 4, j = tid & 15;
        int n = j0 + j;
        float xi = gbD[(0 * 16 + b) * 16 + j] + A.bx[n];
        float xf = gbD[(1 * 16 + b) * 16 + j] + A.bx[512 + n];
        float xo = gbD[(2 * 16 + b) * 16 + j] + A.bx[1024 + n];
        float xc = gbD[(3 * 16 + b) * 16 + j] + A.bx[1536 + n];
        float ymv = A.ymask[ts * NB + b];
        float c1v = ald(&A.c1[b * 512 + n]);
        float h1v = ald(&A.h1[b * 512 + n]);
        float c2 = sigm(xf) * c1v + sigm(xi) * tanh_(xc);
        float h2 = sigm(xo) * tanh_(c2);
        c2 = ymv * c2 + (1.f - ymv) * c1v;
        h2 = ymv * h2 + (1.f - ymv) * h1v;
        ast(&A.h[b * 512 + n], h2);
        ast(&A.c[b * 512 + n], c2);
        int p8 = 0;
        p8 = __builtin_amdgcn_cvt_pk_fp8_f32(h2, h2, p8, 0);
        A.feat8[(size_t)(ts * NB + b) * K4H + n] = (u8)(p8 & 0xff);
      }
      ast(&A.attnum[(par ^ 1) * 16384 + blk * 512 + tid], 0.f);
      ast(&A.attnum[(par ^ 1) * 16384 + blk * 512 + 256 + tid], 0.f);
      ast(&A.qsum[par * 16384 + blk * 512 + tid], 0.f);
      ast(&A.qsum[par * 16384 + blk * 512 + 256 + tid], 0.f);
      if (blk == 0 && tid < NB) ast(&A.attden[(par ^ 1) * NB + tid], 0.f);
    }
    gbar(A.bar, gen); gen++;
  }
}

// ---------------- fused vocab GEMM (fp8) + sum(exp) ----------------
__global__ __launch_bounds__(512, 1) void lse_gemm_fp8(const u8* __restrict__ feat8,
                                                       const float* __restrict__ Wp,
                                                       const float* __restrict__ bp,
                                                       float* __restrict__ lse) {
  extern __shared__ char smem[];
  u8* Bl = (u8*)smem;  // [64][2064] fp8
  const int tid = threadIdx.x;
  const int n0 = blockIdx.x * 64;
  for (int n = 0; n < 64; n++) {
    int gn = n0 + n;
    f32x4v f = {0.f, 0.f, 0.f, 0.f};
    if (gn < VOC)
      f = __builtin_nontemporal_load((const f32x4v*)&Wp[(size_t)gn * K4H + tid * 4]);
    *(u32*)&Bl[n * 2064 + tid * 4] = pkfp8(f.x, f.y, f.z, f.w);
  }
  __syncthreads();
  const int w = tid >> 6, lane = tid & 63;
  const int r16 = lane & 15, kg = lane >> 4;
  bool vj[4];
  float bpj[4];
#pragma unroll
  for (int j = 0; j < 4; j++) {
    int nf = n0 + j * 16 + r16;
    vj[j] = nf < VOC;
    bpj[j] = vj[j] ? bp[nf] : 0.f;
  }
  for (int qq = w; qq < 25; qq += 8) {
    int mrow = qq * 64;
    f32x4 acc[4][4] = {};
    for (int ks = 0; ks < 64; ks++) {
      i64 b0 = *(const i64*)&Bl[(r16) * 2064 + ks * 32 + kg * 8];
      i64 b1 = *(const i64*)&Bl[(16 + r16) * 2064 + ks * 32 + kg * 8];
      i64 b2 = *(const i64*)&Bl[(32 + r16) * 2064 + ks * 32 + kg * 8];
      i64 b3 = *(const i64*)&Bl[(48 + r16) * 2064 + ks * 32 + kg * 8];
#pragma unroll
      for (int s = 0; s < 4; s++) {
        i64 a = *(const i64*)&feat8[(size_t)(mrow + s * 16 + r16) * K4H + ks * 32 + kg * 8];
        acc[s][0] = __builtin_amdgcn_mfma_f32_16x16x32_fp8_fp8(a, b0, acc[s][0], 0, 0, 0);
        acc[s][1] = __builtin_amdgcn_mfma_f32_16x16x32_fp8_fp8(a, b1, acc[s][1], 0, 0, 0);
        acc[s][2] = __builtin_amdgcn_mfma_f32_16x16x32_fp8_fp8(a, b2, acc[s][2], 0, 0, 0);
        acc[s][3] = __builtin_amdgcn_mfma_f32_16x16x32_fp8_fp8(a, b3, acc[s][3], 0, 0, 0);
      }
    }
#pragma unroll
    for (int s = 0; s < 4; s++) {
#pragma unroll
      for (int r = 0; r < 4; r++) {
        float e = 0.f;
#pragma unroll
        for (int j = 0; j < 4; j++)
          if (vj[j]) e += __expf(acc[s][j][r] + bpj[j]);
        e += __shfl_xor(e, 1);
        e += __shfl_xor(e, 2);
        e += __shfl_xor(e, 4);
        e += __shfl_xor(e, 8);
        if (r16 == 0) atomicAdd(&lse[mrow + s * 16 + kg * 4 + r], e);
      }
    }
  }
}

// ---------------- target logit ----------------
__global__ __launch_bounds__(256) void target_logit(const u8* __restrict__ feat8,
                                                    const float* __restrict__ Wp,
                                                    const float* __restrict__ bp,
                                                    const int* __restrict__ yidx,
                                                    float* __restrict__ tlog) {
  int gw = (blockIdx.x * 256 + threadIdx.x) >> 6;
  int lane = threadIdx.x & 63;
  if (gw >= M_ALL) return;
  int yi = yidx[gw];
  const float* wrow = Wp + (size_t)yi * K4H;
  const u8* frow = feat8 + (size_t)gw * K4H;
  float s = 0.f;
#pragma unroll
  for (int i = 0; i < 4; i++) {
    int k = i * 512 + lane * 8;
    uint2 fv = *(const uint2*)&frow[k];
    f32x4v w0 = __builtin_nontemporal_load((const f32x4v*)&wrow[k]);
    f32x4v w1 = __builtin_nontemporal_load((const f32x4v*)&wrow[k + 4]);
    s += __builtin_amdgcn_cvt_f32_fp8(fv.x, 0) * w0.x;
    s += __builtin_amdgcn_cvt_f32_fp8(fv.x, 1) * w0.y;
    s += __builtin_amdgcn_cvt_f32_fp8(fv.x, 2) * w0.z;
    s += __builtin_amdgcn_cvt_f32_fp8(fv.x, 3) * w0.w;
    s += __builtin_amdgcn_cvt_f32_fp8(fv.y, 0) * w1.x;
    s += __builtin_amdgcn_cvt_f32_fp8(fv.y, 1) * w1.y;
    s += __builtin_amdgcn_cvt_f32_fp8(fv.y, 2) * w1.z;
    s += __builtin_amdgcn_cvt_f32_fp8(fv.y, 3) * w1.w;
  }
#pragma unroll
  for (int off = 1; off < 64; off <<= 1) s += __shfl_xor(s, off);
  if (lane == 0) tlog[gw] = s + bp[yi];
}

__global__ void finalize(const float* __restrict__ lse, const float* __restrict__ tlog,
                         const float* __restrict__ ymask, float* __restrict__ out) {
  int b = threadIdx.x;
  if (b < NB) {
    float sc = 0.f, sm = 0.f;
    for (int t = 0; t < T_LEN; t++) {
      int m = t * NB + b;
      float ym = ymask[m];
      sc += (logf(lse[m]) - tlog[m]) * ym;
      sm += ym;
    }
    out[b] = sc / sm;
  }
}

// ---------------- host launcher ----------------
extern "C" void kernel_launch(void* const* d_in, const int* in_sizes, int n_in,
                              void* d_out, int out_size, void* d_ws, size_t ws_size,
                              hipStream_t stream) {
  const float* y_emb = (const float*)d_in[0];
  const float* context = (const float*)d_in[1];
  const float* init_h = (const float*)d_in[2];
  const float* init_c = (const float*)d_in[3];
  const float* x_mask = (const float*)d_in[4];
  const float* y_mask = (const float*)d_in[5];
  const int* y_idx = (const int*)d_in[6];
  const float* W_ih = (const float*)d_in[7];
  const float* W_hh = (const float*)d_in[8];
  const float* b_ih = (const float*)d_in[9];
  const float* b_hh = (const float*)d_in[10];
  const float* Wx = (const float*)d_in[11];
  const float* Ux = (const float*)d_in[12];
  const float* bx = (const float*)d_in[13];
  const float* Wc_att = (const float*)d_in[14];
  const float* b_att = (const float*)d_in[15];
  const float* W_comb = (const float*)d_in[16];
  const float* U_att = (const float*)d_in[17];
  const float* Wp = (const float*)d_in[18];
  const float* bp = (const float*)d_in[19];

  if (ws_size < 60000000ULL) {
    sentinel_kernel<<<1, 64, 0, stream>>>((float*)d_out, (float)(ws_size >> 20));
    return;
  }

  // ---- workspace layout (bytes), end 59,342,848 ----
  char* ws = (char*)d_ws;
  float* lse = (float*)(ws + 0);
  float* attnum = (float*)(ws + 8192);
  float* attden = (float*)(ws + 139264);
  u32* bar = (u32*)(ws + 139392);
  float* qsum = (float*)(ws + 151680);
  float* tlog = (float*)(ws + 282752);
  u16* pctx = (u16*)(ws + 294912);
  u16* ctxb = (u16*)(ws + 13402112);
  u16* Wcb = (u16*)(ws + 26509312);
  u16* yembb = (u16*)(ws + 28606464);
  u16* Wihb = (u16*)(ws + 30244864);
  u16* Whhb = (u16*)(ws + 32342016);
  u16* Wcombb = (u16*)(ws + 34439168);
  u16* Uxb = (u16*)(ws + 36536320);
  u16* Wxb = (u16*)(ws + 38633472);
  float* xW = (float*)(ws + 42827776);
  u8* feat8 = (u8*)(ws + 55934976);
  float* hbuf = (float*)(ws + 59211776);
  float* cbuf = (float*)(ws + 59244544);
  float* h1buf = (float*)(ws + 59277312);
  float* c1buf = (float*)(ws + 59310080);

  hipMemsetAsync(ws, 0, 282752, stream);

  CastArgs ca;
  ca.src[0] = context;  ca.dst[0] = ctxb;
  ca.src[1] = Wc_att;   ca.dst[1] = Wcb;
  ca.src[2] = y_emb;    ca.dst[2] = yembb;
  ca.src[3] = W_ih;     ca.dst[3] = Wihb;
  ca.src[4] = W_hh;     ca.dst[4] = Whhb;
  ca.src[5] = W_comb;   ca.dst[5] = Wcombb;
  ca.src[6] = Ux;       ca.dst[6] = Uxb;
  ca.src[7] = Wx;       ca.dst[7] = Wxb;
  ca.src[8] = y_emb;    ca.dst[8] = (u16*)feat8;
  u32 sz[9] = {819200, 131072, 102400, 131072, 131072, 131072, 131072, 262144, 102400};
  ca.cum[0] = 0;
  for (int i = 0; i < 9; i++) ca.cum[i + 1] = ca.cum[i] + sz[i];
  cast_all<<<(ca.cum[9] + 255) / 256, 256, 0, stream>>>(ca);

  gemm_bf16<0><<<1600, 256, 0, stream>>>(ctxb, Wcb, pctx, b_att, b_att, 6400, 1024, 1024);
  gemm_bf16<1><<<800, 256, 0, stream>>>(yembb, Wihb, xW, b_ih, b_hh, 1600, 2048, 512);

  DecArgs a;
  a.pctx = pctx; a.ctx = ctxb; a.Whh = Whhb; a.Wcomb = Wcombb; a.Uxw = Uxb; a.Wxw = Wxb;
  a.xW = xW; a.bx = bx; a.uatt = U_att; a.xmask = x_mask; a.ymask = y_mask;
  a.init_h = init_h; a.init_c = init_c;
  a.h = hbuf; a.c = cbuf; a.h1 = h1buf; a.c1 = c1buf; a.qsum = qsum;
  a.attnum = attnum; a.attden = attden; a.feat8 = feat8; a.bar = bar;
  hipFuncSetAttribute(reinterpret_cast<const void*>(decoder_coop),
                      hipFuncAttributeMaxDynamicSharedMemorySize, 160448);
  decoder_coop<<<256, 256, 160448, stream>>>(a);

  hipFuncSetAttribute(reinterpret_cast<const void*>(lse_gemm_fp8),
                      hipFuncAttributeMaxDynamicSharedMemorySize, 132096);
  lse_gemm_fp8<<<782, 512, 132096, stream>>>(feat8, Wp, bp, lse);

  target_logit<<<400, 256, 0, stream>>>(feat8, Wp, bp, y_idx, tlog);
  finalize<<<1, 64, 0, stream>>>(lse, tlog, y_mask, (float*)d_out);
}

// Round 12
// 5051.798 us; speedup vs baseline: 1.6523x; 1.0167x over previous
//
#include <hip/hip_runtime.h>
#include <stdint.h>

typedef unsigned int u32;
typedef unsigned short u16;
typedef unsigned char u8;
typedef long long i64;
typedef __attribute__((ext_vector_type(4))) float f32x4;
typedef __attribute__((ext_vector_type(4))) float f32x4v;
typedef __attribute__((ext_vector_type(8))) short bf16x8;

#define T_LEN 100
#define S_LEN 400
#define NB 16
#define HD 512
#define CTXD 1024
#define VOC 50000
#define K4H 2048
#define M_ALL 1600

static __device__ __forceinline__ float bf2f(u16 v) {
  union { u32 u; float f; } c; c.u = ((u32)v) << 16; return c.f;
}
static __device__ __forceinline__ u16 f2bf(float f) {
  union { float f; u32 u; } c; c.f = f;
  return (u16)((c.u + 0x7fffu + ((c.u >> 16) & 1u)) >> 16);
}
static __device__ __forceinline__ u32 pack2(float a, float b) {
  return (u32)f2bf(a) | ((u32)f2bf(b) << 16);
}
static __device__ __forceinline__ uint4 pack8(float4 a, float4 b) {
  return make_uint4(pack2(a.x, a.y), pack2(a.z, a.w), pack2(b.x, b.y), pack2(b.z, b.w));
}
static __device__ __forceinline__ uint4 pack8v(f32x4v a, f32x4v b) {
  return make_uint4(pack2(a.x, a.y), pack2(a.z, a.w), pack2(b.x, b.y), pack2(b.z, b.w));
}
static __device__ __forceinline__ u32 pkfp8(float x, float y, float z, float w) {
  int p = 0;
  p = __builtin_amdgcn_cvt_pk_fp8_f32(x, y, p, 0);
  p = __builtin_amdgcn_cvt_pk_fp8_f32(z, w, p, 1);
  return (u32)p;
}
static __device__ __forceinline__ float sigm(float x) { return 1.f / (1.f + __expf(-x)); }
static __device__ __forceinline__ float tanh_(float x) {
  float e = __expf(2.f * x);
  return 1.f - 2.f / (e + 1.f);
}
// coherent scalar load/store (agent scope; bypasses stale caches)
static __device__ __forceinline__ float ald(const float* p) {
  return __hip_atomic_load(p, __ATOMIC_RELAXED, __HIP_MEMORY_SCOPE_AGENT);
}
static __device__ __forceinline__ void ast(float* p, float v) {
  __hip_atomic_store(p, v, __ATOMIC_RELAXED, __HIP_MEMORY_SCOPE_AGENT);
}
// coherent 16B load, single
static __device__ __forceinline__ f32x4v cld4(const float* p) {
  f32x4v v;
  asm volatile("global_load_dwordx4 %0, %1, off sc0 sc1\n\t"
               "s_waitcnt vmcnt(0)"
               : "=&v"(v) : "v"(p) : "memory");
  return v;
}
// coherent 16B loads, batch of 8 with one waitcnt
static __device__ __forceinline__ void cld8(
    const float* p0, const float* p1, const float* p2, const float* p3,
    const float* p4, const float* p5, const float* p6, const float* p7,
    f32x4v& v0, f32x4v& v1, f32x4v& v2, f32x4v& v3,
    f32x4v& v4, f32x4v& v5, f32x4v& v6, f32x4v& v7) {
  asm volatile(
      "global_load_dwordx4 %0, %8, off sc0 sc1\n\t"
      "global_load_dwordx4 %1, %9, off sc0 sc1\n\t"
      "global_load_dwordx4 %2, %10, off sc0 sc1\n\t"
      "global_load_dwordx4 %3, %11, off sc0 sc1\n\t"
      "global_load_dwordx4 %4, %12, off sc0 sc1\n\t"
      "global_load_dwordx4 %5, %13, off sc0 sc1\n\t"
      "global_load_dwordx4 %6, %14, off sc0 sc1\n\t"
      "global_load_dwordx4 %7, %15, off sc0 sc1\n\t"
      "s_waitcnt vmcnt(0)"
      : "=&v"(v0), "=&v"(v1), "=&v"(v2), "=&v"(v3),
        "=&v"(v4), "=&v"(v5), "=&v"(v6), "=&v"(v7)
      : "v"(p0), "v"(p1), "v"(p2), "v"(p3), "v"(p4), "v"(p5), "v"(p6), "v"(p7)
      : "memory");
}
// producer signal / consumer wait (monotonic counters at LLC)
static __device__ __forceinline__ void sig(u32* ctr) {
  __hip_atomic_fetch_add(ctr, 1u, __ATOMIC_RELAXED, __HIP_MEMORY_SCOPE_AGENT);
}
static __device__ __forceinline__ void waitge(u32* ctr, u32 tgt) {
  while (__hip_atomic_load(ctr, __ATOMIC_RELAXED, __HIP_MEMORY_SCOPE_AGENT) < tgt)
    __builtin_amdgcn_s_sleep(1);
}

__global__ void sentinel_kernel(float* out, float v) {
  if (threadIdx.x < NB) out[threadIdx.x] = v;
}

// ---------------- fused cast kernel ----------------
struct CastArgs {
  const float* src[9];
  u16* dst[9];
  u32 cum[10];
};

__global__ __launch_bounds__(256) void cast_all(CastArgs A) {
  u32 i = blockIdx.x * 256 + threadIdx.x;
  if (i >= A.cum[9]) return;
  int seg = 0;
  while (i >= A.cum[seg + 1]) seg++;
  u32 li = i - A.cum[seg];
  const float* s = A.src[seg];
  f32x4v a = __builtin_nontemporal_load((const f32x4v*)&s[li * 8]);
  f32x4v b = __builtin_nontemporal_load((const f32x4v*)&s[li * 8 + 4]);
  if (seg < 8) {
    *(uint4*)&A.dst[seg][li * 8] = pack8v(a, b);
  } else {  // y_emb -> feat8[:, 1536:2048] (fp8)
    u32 m = li >> 6, k8 = (li & 63) << 3;
    u8* f8 = (u8*)A.dst[8];
    uint2 t;
    t.x = pkfp8(a.x, a.y, a.z, a.w);
    t.y = pkfp8(b.x, b.y, b.z, b.w);
    *(uint2*)&f8[(size_t)m * K4H + 1536 + k8] = t;
  }
}

// ---------------- generic bf16 MFMA GEMM ----------------
template <int MODE>
__global__ __launch_bounds__(256) void gemm_bf16(const u16* __restrict__ A,
                                                 const u16* __restrict__ Bw,
                                                 void* __restrict__ out,
                                                 const float* __restrict__ bias1,
                                                 const float* __restrict__ bias2,
                                                 int M, int N, int K) {
  __shared__ u16 As[64][40];
  __shared__ u16 Bs[64][40];
  int nb = N / 64;
  int m0 = (blockIdx.x / nb) * 64;
  int n0 = (blockIdx.x % nb) * 64;
  int tid = threadIdx.x;
  int lane = tid & 63;
  int w = tid >> 6;
  int wm = (w >> 1) * 32, wn = (w & 1) * 32;
  f32x4 acc[2][2] = {};
  int arow = tid >> 2, achk = (tid & 3) * 8;
  for (int k0 = 0; k0 < K; k0 += 32) {
    __syncthreads();
    *(uint4*)&As[arow][achk] = *(const uint4*)&A[(size_t)(m0 + arow) * K + k0 + achk];
    *(uint4*)&Bs[arow][achk] = *(const uint4*)&Bw[(size_t)(n0 + arow) * K + k0 + achk];
    __syncthreads();
    int r = lane & 15, kg = lane >> 4;
    bf16x8 a0 = *(const bf16x8*)&As[wm + r][kg * 8];
    bf16x8 a1 = *(const bf16x8*)&As[wm + 16 + r][kg * 8];
    bf16x8 b0 = *(const bf16x8*)&Bs[wn + r][kg * 8];
    bf16x8 b1 = *(const bf16x8*)&Bs[wn + 16 + r][kg * 8];
    acc[0][0] = __builtin_amdgcn_mfma_f32_16x16x32_bf16(a0, b0, acc[0][0], 0, 0, 0);
    acc[0][1] = __builtin_amdgcn_mfma_f32_16x16x32_bf16(a0, b1, acc[0][1], 0, 0, 0);
    acc[1][0] = __builtin_amdgcn_mfma_f32_16x16x32_bf16(a1, b0, acc[1][0], 0, 0, 0);
    acc[1][1] = __builtin_amdgcn_mfma_f32_16x16x32_bf16(a1, b1, acc[1][1], 0, 0, 0);
  }
  int col = lane & 15, rg = lane >> 4;
#pragma unroll
  for (int fi = 0; fi < 2; fi++)
#pragma unroll
    for (int fj = 0; fj < 2; fj++)
#pragma unroll
      for (int r = 0; r < 4; r++) {
        int m = m0 + wm + fi * 16 + rg * 4 + r;
        int n = n0 + wn + fj * 16 + col;
        float v = acc[fi][fj][r] + bias1[n];
        if constexpr (MODE == 1) {
          v += bias2[n];
          ((float*)out)[(size_t)m * N + n] = v;
        } else {
          ((u16*)out)[(size_t)m * N + n] = f2bf(v);
        }
      }
}

// ---------------- persistent decoder ----------------
struct DecArgs {
  const u16 *pctx, *ctx, *Whh, *Wcomb, *Uxw, *Wxw;
  const float *xW, *bx, *uatt, *xmask, *ymask, *init_h, *init_c;
  float *h, *c, *h1, *c1, *qsum, *attnum, *attden;
  u8* feat8;
  u32* bar;
};

// Sync: 3 monotonic done-counters (qdone=bar[0], cdone=bar[64], h2done=bar[128]).
// __syncthreads before each sig() drains every wave's vmcnt (compiler semantics),
// so counter increments imply all the phase's stores/atomics are globally visible.
__global__ __launch_bounds__(256, 1) void decoder_coop(DecArgs A) {
  extern __shared__ char smem[];
  u16* pctx_l = (u16*)smem;
  u16* ctx_l = (u16*)(smem + 51200);
  float* ua_lp = (float*)(smem + 102400);
  float* xm_l = (float*)(smem + 106752);
  char* un = smem + 106880;

  const int tid = threadIdx.x;
  const int blk = blockIdx.x;
  const int lane = tid & 63, w = tid >> 6;
  const int r16 = lane & 15, kg = lane >> 4;
  const int bK = blk & 15;
  const int s0 = (blk >> 4) * 25;
  u32* qdone = A.bar;
  u32* cdone = A.bar + 64;
  u32* h2done = A.bar + 128;

  // ---- one-time prefill of persistent LDS ----
  for (int idx = tid; idx < 25 * 128; idx += 256) {
    int i = idx >> 7, c8 = (idx & 127) << 3;
    *(uint4*)&pctx_l[i * 1024 + c8] =
        *(const uint4*)&A.pctx[((size_t)(s0 + i) * NB + bK) * CTXD + c8];
    *(uint4*)&ctx_l[i * 1024 + c8] =
        *(const uint4*)&A.ctx[((size_t)(s0 + i) * NB + bK) * CTXD + c8];
  }
  {
    int c0 = tid * 4;
    int p = (c0 >> 4) * 17 + (c0 & 15);
#pragma unroll
    for (int j = 0; j < 4; j++) ua_lp[p + j] = A.uatt[c0 + j];
  }
  if (tid < 25) xm_l[tid] = A.xmask[(s0 + tid) * NB + bK];

  for (int ts = 0; ts < T_LEN; ts++) {
    const int par = ts & 1;
    // ========= phase A: LSTM1 + q partials -> qsum (blocks 0..15) =========
    if (blk < 16) {
      if (tid == 0) waitge(h2done, 32u * (u32)ts);
      __syncthreads();
      u16* Al = (u16*)un;
      float* gbA = (float*)(un + 16640);
      u16* h1c1 = (u16*)(un + 24832);
      const float* hs = ts ? A.h : A.init_h;
      const float* cs = ts ? A.c : A.init_c;
      {
        const int b0_ = tid >> 6, k80 = (tid & 63) << 3;
        const int b1_ = (256 + tid) >> 6, k81 = ((256 + tid) & 63) << 3;
        const int b2_ = (512 + tid) >> 6, k82 = ((512 + tid) & 63) << 3;
        const int b3_ = (768 + tid) >> 6, k83 = ((768 + tid) & 63) << 3;
        f32x4v v0, v1, v2, v3, v4, v5, v6, v7;
        cld8(&hs[b0_ * 512 + k80], &hs[b0_ * 512 + k80 + 4],
             &hs[b1_ * 512 + k81], &hs[b1_ * 512 + k81 + 4],
             &hs[b2_ * 512 + k82], &hs[b2_ * 512 + k82 + 4],
             &hs[b3_ * 512 + k83], &hs[b3_ * 512 + k83 + 4],
             v0, v1, v2, v3, v4, v5, v6, v7);
        *(uint4*)&Al[b0_ * 520 + k80] = pack8v(v0, v1);
        *(uint4*)&Al[b1_ * 520 + k81] = pack8v(v2, v3);
        *(uint4*)&Al[b2_ * 520 + k82] = pack8v(v4, v5);
        *(uint4*)&Al[b3_ * 520 + k83] = pack8v(v6, v7);
      }
      __syncthreads();
      const int j0 = blk * 32;
      {
        f32x4 acc0 = {}, acc1 = {};
        const size_t row0 = (size_t)(w * 512 + j0 + r16) * 512;
        const size_t row1 = (size_t)(w * 512 + j0 + 16 + r16) * 512;
#pragma unroll
        for (int ks = 0; ks < 16; ks++) {
          bf16x8 a = *(const bf16x8*)&Al[r16 * 520 + ks * 32 + kg * 8];
          bf16x8 b0 = *(const bf16x8*)&A.Whh[row0 + ks * 32 + kg * 8];
          bf16x8 b1 = *(const bf16x8*)&A.Whh[row1 + ks * 32 + kg * 8];
          acc0 = __builtin_amdgcn_mfma_f32_16x16x32_bf16(a, b0, acc0, 0, 0, 0);
          acc1 = __builtin_amdgcn_mfma_f32_16x16x32_bf16(a, b1, acc1, 0, 0, 0);
        }
#pragma unroll
        for (int r = 0; r < 4; r++) {
          gbA[(w * 16 + kg * 4 + r) * 32 + r16] = acc0[r];
          gbA[(w * 16 + kg * 4 + r) * 32 + 16 + r16] = acc1[r];
        }
      }
      __syncthreads();
#pragma unroll
      for (int i = 0; i < 2; i++) {
        int idx = i * 256 + tid;
        int b = idx >> 5, j = idx & 31;
        int n = j0 + j;
        const float* xw = &A.xW[(size_t)(ts * NB + b) * K4H];
        float gi = gbA[(0 * 16 + b) * 32 + j] + xw[n];
        float gf = gbA[(1 * 16 + b) * 32 + j] + xw[512 + n];
        float gg = gbA[(2 * 16 + b) * 32 + j] + xw[1024 + n];
        float go = gbA[(3 * 16 + b) * 32 + j] + xw[1536 + n];
        float ymv = A.ymask[ts * NB + b];
        float c_old = ald(&cs[b * 512 + n]);
        float h_old = ald(&hs[b * 512 + n]);
        float c1v = sigm(gf) * c_old + sigm(gi) * tanh_(gg);
        float h1v = sigm(go) * tanh_(c1v);
        h1v = ymv * h1v + (1.f - ymv) * h_old;
        c1v = ymv * c1v + (1.f - ymv) * c_old;
        ast(&A.h1[b * 512 + n], h1v);
        ast(&A.c1[b * 512 + n], c1v);
        h1c1[b * 72 + j] = f2bf(h1v);
        h1c1[b * 72 + 32 + j] = f2bf(c1v);
      }
      __syncthreads();
      {
        bf16x8 a0 = *(const bf16x8*)&h1c1[r16 * 72 + kg * 8];
        bf16x8 a1 = *(const bf16x8*)&h1c1[r16 * 72 + 32 + kg * 8];
        float* qs = A.qsum + par * 16384;
        for (int nt = w; nt < 64; nt += 4) {
          int n = nt * 16 + r16;
          bf16x8 b0 = *(const bf16x8*)&A.Wcomb[(size_t)n * 1024 + j0 + kg * 8];
          bf16x8 b1 = *(const bf16x8*)&A.Wcomb[(size_t)n * 1024 + 512 + j0 + kg * 8];
          f32x4 acc = {};
          acc = __builtin_amdgcn_mfma_f32_16x16x32_bf16(a0, b0, acc, 0, 0, 0);
          acc = __builtin_amdgcn_mfma_f32_16x16x32_bf16(a1, b1, acc, 0, 0, 0);
#pragma unroll
          for (int r = 0; r < 4; r++)
            atomicAdd(&qs[(kg * 4 + r) * 1024 + nt * 16 + r16], acc[r]);
        }
      }
      __syncthreads();  // drains all waves' qsum atomics
      if (tid == 0) sig(qdone);
    }
    // ========= phase C: attention (all 256 blocks) =========
    {
      if (tid == 0) waitge(qdone, 16u * (u32)(ts + 1));
      __syncthreads();
      float* q_lp = (float*)un;
      float* p_l = (float*)(un + 4352);
      {
        int c0 = tid * 4;
        f32x4v qv = cld4(&A.qsum[par * 16384 + bK * 1024 + c0]);
        int p = (c0 >> 4) * 17 + (c0 & 15);
        q_lp[p] = qv.x; q_lp[p + 1] = qv.y; q_lp[p + 2] = qv.z; q_lp[p + 3] = qv.w;
      }
      __syncthreads();
      for (int i = w; i < 25; i += 4) {
        const u16* prow = &pctx_l[i * 1024 + lane * 16];
        float s = 0.f;
#pragma unroll
        for (int half = 0; half < 2; half++) {
          bf16x8 pv = *(const bf16x8*)&prow[half * 8];
#pragma unroll
          for (int e = 0; e < 8; e++) {
            int cc = lane * 17 + half * 8 + e;
            s += tanh_(bf2f((u16)pv[e]) + q_lp[cc]) * ua_lp[cc];
          }
        }
#pragma unroll
        for (int off = 1; off < 64; off <<= 1) s += __shfl_xor(s, off);
        if (lane == 0) {
          float xm = xm_l[i];
          p_l[i] = __expf(s * xm) * xm;
        }
      }
      __syncthreads();
      const int c4 = tid << 2;
      float n0 = 0, n1 = 0, n2 = 0, n3 = 0;
#pragma unroll 5
      for (int i = 0; i < 25; i++) {
        float pv = p_l[i];
        uint2 ld = *(const uint2*)&ctx_l[i * 1024 + c4];
        n0 += pv * bf2f((u16)(ld.x & 0xffff));
        n1 += pv * bf2f((u16)(ld.x >> 16));
        n2 += pv * bf2f((u16)(ld.y & 0xffff));
        n3 += pv * bf2f((u16)(ld.y >> 16));
      }
      float* dst = &A.attnum[par * 16384 + bK * 1024 + c4];
      atomicAdd(dst + 0, n0);
      atomicAdd(dst + 1, n1);
      atomicAdd(dst + 2, n2);
      atomicAdd(dst + 3, n3);
      if (tid == 0) {
        float d = 0.f;
        for (int i = 0; i < 25; i++) d += p_l[i];
        atomicAdd(&A.attden[par * NB + bK], d);
      }
      __syncthreads();  // drains attention atomics
      if (tid == 0) sig(cdone);
    }
    // ========= phase D: gates2 + state update (blocks 0..31) =========
    if (blk < 32) {
      if (tid == 0) waitge(cdone, 256u * (u32)(ts + 1));
      __syncthreads();
      u16* AlD = (u16*)un;
      float* gbD = (float*)(un + 49408);
      float* attden_l = (float*)(un + 53504);
      if (tid < NB) attden_l[tid] = ald(&A.attden[par * NB + tid]);
      {
        const int b0_ = tid >> 6, k80 = (tid & 63) << 3;
        const int b1_ = (256 + tid) >> 6, k81 = ((256 + tid) & 63) << 3;
        const int b2_ = (512 + tid) >> 6, k82 = ((512 + tid) & 63) << 3;
        const int b3_ = (768 + tid) >> 6, k83 = ((768 + tid) & 63) << 3;
        f32x4v v0, v1, v2, v3, v4, v5, v6, v7;
        cld8(&A.h1[b0_ * 512 + k80], &A.h1[b0_ * 512 + k80 + 4],
             &A.h1[b1_ * 512 + k81], &A.h1[b1_ * 512 + k81 + 4],
             &A.h1[b2_ * 512 + k82], &A.h1[b2_ * 512 + k82 + 4],
             &A.h1[b3_ * 512 + k83], &A.h1[b3_ * 512 + k83 + 4],
             v0, v1, v2, v3, v4, v5, v6, v7);
        *(uint4*)&AlD[b0_ * 1544 + k80] = pack8v(v0, v1);
        *(uint4*)&AlD[b1_ * 1544 + k81] = pack8v(v2, v3);
        *(uint4*)&AlD[b2_ * 1544 + k82] = pack8v(v4, v5);
        *(uint4*)&AlD[b3_ * 1544 + k83] = pack8v(v6, v7);
      }
      __syncthreads();
      {
        const float* base = &A.attnum[par * 16384];
        const int c4 = tid << 2;
        f32x4v a0, a1, a2, a3, a4, a5, a6, a7;
        cld8(base + 0 * 1024 + c4, base + 1 * 1024 + c4, base + 2 * 1024 + c4,
             base + 3 * 1024 + c4, base + 4 * 1024 + c4, base + 5 * 1024 + c4,
             base + 6 * 1024 + c4, base + 7 * 1024 + c4,
             a0, a1, a2, a3, a4, a5, a6, a7);
#define ATT_ST(i, vv)                                                        \
  {                                                                          \
    float rd = 1.f / attden_l[i];                                            \
    uint2 t;                                                                 \
    t.x = pack2(vv.x * rd, vv.y * rd);                                       \
    t.y = pack2(vv.z * rd, vv.w * rd);                                       \
    *(uint2*)&AlD[(i) * 1544 + 512 + c4] = t;                                \
  }
        ATT_ST(0, a0) ATT_ST(1, a1) ATT_ST(2, a2) ATT_ST(3, a3)
        ATT_ST(4, a4) ATT_ST(5, a5) ATT_ST(6, a6) ATT_ST(7, a7)
        cld8(base + 8 * 1024 + c4, base + 9 * 1024 + c4, base + 10 * 1024 + c4,
             base + 11 * 1024 + c4, base + 12 * 1024 + c4, base + 13 * 1024 + c4,
             base + 14 * 1024 + c4, base + 15 * 1024 + c4,
             a0, a1, a2, a3, a4, a5, a6, a7);
        ATT_ST(8, a0) ATT_ST(9, a1) ATT_ST(10, a2) ATT_ST(11, a3)
        ATT_ST(12, a4) ATT_ST(13, a5) ATT_ST(14, a6) ATT_ST(15, a7)
#undef ATT_ST
      }
      __syncthreads();
      if (blk < 16) {
        const u16* arow = &AlD[blk * 1544 + 512];
        int c4 = tid * 4;
        u32 p = pkfp8(bf2f(arow[c4]), bf2f(arow[c4 + 1]), bf2f(arow[c4 + 2]),
                      bf2f(arow[c4 + 3]));
        *(u32*)&A.feat8[(size_t)(ts * NB + blk) * K4H + 512 + c4] = p;
      }
      const int j0 = blk * 16;
      f32x4 acc = {};
      const size_t rowU = (size_t)(w * 512 + j0 + r16) * 512;
      const size_t rowW = (size_t)(w * 512 + j0 + r16) * 1024;
#pragma unroll
      for (int ks = 0; ks < 16; ks++) {
        bf16x8 a = *(const bf16x8*)&AlD[r16 * 1544 + ks * 32 + kg * 8];
        bf16x8 b0 = *(const bf16x8*)&A.Uxw[rowU + ks * 32 + kg * 8];
        acc = __builtin_amdgcn_mfma_f32_16x16x32_bf16(a, b0, acc, 0, 0, 0);
      }
#pragma unroll
      for (int ks = 16; ks < 48; ks++) {
        bf16x8 a = *(const bf16x8*)&AlD[r16 * 1544 + ks * 32 + kg * 8];
        bf16x8 b0 = *(const bf16x8*)&A.Wxw[rowW + (ks - 16) * 32 + kg * 8];
        acc = __builtin_amdgcn_mfma_f32_16x16x32_bf16(a, b0, acc, 0, 0, 0);
      }
#pragma unroll
      for (int r = 0; r < 4; r++) gbD[(w * 16 + kg * 4 + r) * 16 + r16] = acc[r];
      __syncthreads();
      {
        int b = tid >> 4, j = tid & 15;
        int n = j0 + j;
        float xi = gbD[(0 * 16 + b) * 16 + j] + A.bx[n];
        float xf = gbD[(1 * 16 + b) * 16 + j] + A.bx[512 + n];
        float xo = gbD[(2 * 16 + b) * 16 + j] + A.bx[1024 + n];
        float xc = gbD[(3 * 16 + b) * 16 + j] + A.bx[1536 + n];
        float ymv = A.ymask[ts * NB + b];
        float c1v = ald(&A.c1[b * 512 + n]);
        float h1v = ald(&A.h1[b * 512 + n]);
        float c2 = sigm(xf) * c1v + sigm(xi) * tanh_(xc);
        float h2 = sigm(xo) * tanh_(c2);
        c2 = ymv * c2 + (1.f - ymv) * c1v;
        h2 = ymv * h2 + (1.f - ymv) * h1v;
        ast(&A.h[b * 512 + n], h2);
        ast(&A.c[b * 512 + n], c2);
        int p8 = 0;
        p8 = __builtin_amdgcn_cvt_pk_fp8_f32(h2, h2, p8, 0);
        A.feat8[(size_t)(ts * NB + b) * K4H + n] = (u8)(p8 & 0xff);
      }
      // zero consumed-parity buffers for future steps
      ast(&A.attnum[(par ^ 1) * 16384 + blk * 512 + tid], 0.f);
      ast(&A.attnum[(par ^ 1) * 16384 + blk * 512 + 256 + tid], 0.f);
      ast(&A.qsum[par * 16384 + blk * 512 + tid], 0.f);
      ast(&A.qsum[par * 16384 + blk * 512 + 256 + tid], 0.f);
      if (blk == 0 && tid < NB) ast(&A.attden[(par ^ 1) * NB + tid], 0.f);
      __syncthreads();  // drains h/c/zero stores
      if (tid == 0) sig(h2done);
    }
  }
}

// ---------------- fused vocab GEMM (fp8) + sum(exp) ----------------
__global__ __launch_bounds__(512, 1) void lse_gemm_fp8(const u8* __restrict__ feat8,
                                                       const float* __restrict__ Wp,
                                                       const float* __restrict__ bp,
                                                       float* __restrict__ lse) {
  extern __shared__ char smem[];
  u8* Bl = (u8*)smem;  // [64][2064] fp8
  const int tid = threadIdx.x;
  const int n0 = blockIdx.x * 64;
  for (int n = 0; n < 64; n++) {
    int gn = n0 + n;
    f32x4v f = {0.f, 0.f, 0.f, 0.f};
    if (gn < VOC)
      f = __builtin_nontemporal_load((const f32x4v*)&Wp[(size_t)gn * K4H + tid * 4]);
    *(u32*)&Bl[n * 2064 + tid * 4] = pkfp8(f.x, f.y, f.z, f.w);
  }
  __syncthreads();
  const int w = tid >> 6, lane = tid & 63;
  const int r16 = lane & 15, kg = lane >> 4;
  bool vj[4];
  float bpj[4];
#pragma unroll
  for (int j = 0; j < 4; j++) {
    int nf = n0 + j * 16 + r16;
    vj[j] = nf < VOC;
    bpj[j] = vj[j] ? bp[nf] : 0.f;
  }
  for (int qq = w; qq < 25; qq += 8) {
    int mrow = qq * 64;
    f32x4 acc[4][4] = {};
    for (int ks = 0; ks < 64; ks++) {
      i64 b0 = *(const i64*)&Bl[(r16) * 2064 + ks * 32 + kg * 8];
      i64 b1 = *(const i64*)&Bl[(16 + r16) * 2064 + ks * 32 + kg * 8];
      i64 b2 = *(const i64*)&Bl[(32 + r16) * 2064 + ks * 32 + kg * 8];
      i64 b3 = *(const i64*)&Bl[(48 + r16) * 2064 + ks * 32 + kg * 8];
#pragma unroll
      for (int s = 0; s < 4; s++) {
        i64 a = *(const i64*)&feat8[(size_t)(mrow + s * 16 + r16) * K4H + ks * 32 + kg * 8];
        acc[s][0] = __builtin_amdgcn_mfma_f32_16x16x32_fp8_fp8(a, b0, acc[s][0], 0, 0, 0);
        acc[s][1] = __builtin_amdgcn_mfma_f32_16x16x32_fp8_fp8(a, b1, acc[s][1], 0, 0, 0);
        acc[s][2] = __builtin_amdgcn_mfma_f32_16x16x32_fp8_fp8(a, b2, acc[s][2], 0, 0, 0);
        acc[s][3] = __builtin_amdgcn_mfma_f32_16x16x32_fp8_fp8(a, b3, acc[s][3], 0, 0, 0);
      }
    }
#pragma unroll
    for (int s = 0; s < 4; s++) {
#pragma unroll
      for (int r = 0; r < 4; r++) {
        float e = 0.f;
#pragma unroll
        for (int j = 0; j < 4; j++)
          if (vj[j]) e += __expf(acc[s][j][r] + bpj[j]);
        e += __shfl_xor(e, 1);
        e += __shfl_xor(e, 2);
        e += __shfl_xor(e, 4);
        e += __shfl_xor(e, 8);
        if (r16 == 0) atomicAdd(&lse[mrow + s * 16 + kg * 4 + r], e);
      }
    }
  }
}

// ---------------- target logit ----------------
__global__ __launch_bounds__(256) void target_logit(const u8* __restrict__ feat8,
                                                    const float* __restrict__ Wp,
                                                    const float* __restrict__ bp,
                                                    const int* __restrict__ yidx,
                                                    float* __restrict__ tlog) {
  int gw = (blockIdx.x * 256 + threadIdx.x) >> 6;
  int lane = threadIdx.x & 63;
  if (gw >= M_ALL) return;
  int yi = yidx[gw];
  const float* wrow = Wp + (size_t)yi * K4H;
  const u8* frow = feat8 + (size_t)gw * K4H;
  float s = 0.f;
#pragma unroll
  for (int i = 0; i < 4; i++) {
    int k = i * 512 + lane * 8;
    uint2 fv = *(const uint2*)&frow[k];
    f32x4v w0 = __builtin_nontemporal_load((const f32x4v*)&wrow[k]);
    f32x4v w1 = __builtin_nontemporal_load((const f32x4v*)&wrow[k + 4]);
    s += __builtin_amdgcn_cvt_f32_fp8(fv.x, 0) * w0.x;
    s += __builtin_amdgcn_cvt_f32_fp8(fv.x, 1) * w0.y;
    s += __builtin_amdgcn_cvt_f32_fp8(fv.x, 2) * w0.z;
    s += __builtin_amdgcn_cvt_f32_fp8(fv.x, 3) * w0.w;
    s += __builtin_amdgcn_cvt_f32_fp8(fv.y, 0) * w1.x;
    s += __builtin_amdgcn_cvt_f32_fp8(fv.y, 1) * w1.y;
    s += __builtin_amdgcn_cvt_f32_fp8(fv.y, 2) * w1.z;
    s += __builtin_amdgcn_cvt_f32_fp8(fv.y, 3) * w1.w;
  }
#pragma unroll
  for (int off = 1; off < 64; off <<= 1) s += __shfl_xor(s, off);
  if (lane == 0) tlog[gw] = s + bp[yi];
}

__global__ void finalize(const float* __restrict__ lse, const float* __restrict__ tlog,
                         const float* __restrict__ ymask, float* __restrict__ out) {
  int b = threadIdx.x;
  if (b < NB) {
    float sc = 0.f, sm = 0.f;
    for (int t = 0; t < T_LEN; t++) {
      int m = t * NB + b;
      float ym = ymask[m];
      sc += (logf(lse[m]) - tlog[m]) * ym;
      sm += ym;
    }
    out[b] = sc / sm;
  }
}

// ---------------- host launcher ----------------
extern "C" void kernel_launch(void* const* d_in, const int* in_sizes, int n_in,
                              void* d_out, int out_size, void* d_ws, size_t ws_size,
                              hipStream_t stream) {
  const float* y_emb = (const float*)d_in[0];
  const float* context = (const float*)d_in[1];
  const float* init_h = (const float*)d_in[2];
  const float* init_c = (const float*)d_in[3];
  const float* x_mask = (const float*)d_in[4];
  const float* y_mask = (const float*)d_in[5];
  const int* y_idx = (const int*)d_in[6];
  const float* W_ih = (const float*)d_in[7];
  const float* W_hh = (const float*)d_in[8];
  const float* b_ih = (const float*)d_in[9];
  const float* b_hh = (const float*)d_in[10];
  const float* Wx = (const float*)d_in[11];
  const float* Ux = (const float*)d_in[12];
  const float* bx = (const float*)d_in[13];
  const float* Wc_att = (const float*)d_in[14];
  const float* b_att = (const float*)d_in[15];
  const float* W_comb = (const float*)d_in[16];
  const float* U_att = (const float*)d_in[17];
  const float* Wp = (const float*)d_in[18];
  const float* bp = (const float*)d_in[19];

  if (ws_size < 60000000ULL) {
    sentinel_kernel<<<1, 64, 0, stream>>>((float*)d_out, (float)(ws_size >> 20));
    return;
  }

  // ---- workspace layout (bytes), end 59,342,848 ----
  char* ws = (char*)d_ws;
  float* lse = (float*)(ws + 0);
  float* attnum = (float*)(ws + 8192);
  float* attden = (float*)(ws + 139264);
  u32* bar = (u32*)(ws + 139392);
  float* qsum = (float*)(ws + 151680);
  float* tlog = (float*)(ws + 282752);
  u16* pctx = (u16*)(ws + 294912);
  u16* ctxb = (u16*)(ws + 13402112);
  u16* Wcb = (u16*)(ws + 26509312);
  u16* yembb = (u16*)(ws + 28606464);
  u16* Wihb = (u16*)(ws + 30244864);
  u16* Whhb = (u16*)(ws + 32342016);
  u16* Wcombb = (u16*)(ws + 34439168);
  u16* Uxb = (u16*)(ws + 36536320);
  u16* Wxb = (u16*)(ws + 38633472);
  float* xW = (float*)(ws + 42827776);
  u8* feat8 = (u8*)(ws + 55934976);
  float* hbuf = (float*)(ws + 59211776);
  float* cbuf = (float*)(ws + 59244544);
  float* h1buf = (float*)(ws + 59277312);
  float* c1buf = (float*)(ws + 59310080);

  hipMemsetAsync(ws, 0, 282752, stream);

  CastArgs ca;
  ca.src[0] = context;  ca.dst[0] = ctxb;
  ca.src[1] = Wc_att;   ca.dst[1] = Wcb;
  ca.src[2] = y_emb;    ca.dst[2] = yembb;
  ca.src[3] = W_ih;     ca.dst[3] = Wihb;
  ca.src[4] = W_hh;     ca.dst[4] = Whhb;
  ca.src[5] = W_comb;   ca.dst[5] = Wcombb;
  ca.src[6] = Ux;       ca.dst[6] = Uxb;
  ca.src[7] = Wx;       ca.dst[7] = Wxb;
  ca.src[8] = y_emb;    ca.dst[8] = (u16*)feat8;
  u32 sz[9] = {819200, 131072, 102400, 131072, 131072, 131072, 131072, 262144, 102400};
  ca.cum[0] = 0;
  for (int i = 0; i < 9; i++) ca.cum[i + 1] = ca.cum[i] + sz[i];
  cast_all<<<(ca.cum[9] + 255) / 256, 256, 0, stream>>>(ca);

  gemm_bf16<0><<<1600, 256, 0, stream>>>(ctxb, Wcb, pctx, b_att, b_att, 6400, 1024, 1024);
  gemm_bf16<1><<<800, 256, 0, stream>>>(yembb, Wihb, xW, b_ih, b_hh, 1600, 2048, 512);

  DecArgs a;
  a.pctx = pctx; a.ctx = ctxb; a.Whh = Whhb; a.Wcomb = Wcombb; a.Uxw = Uxb; a.Wxw = Wxb;
  a.xW = xW; a.bx = bx; a.uatt = U_att; a.xmask = x_mask; a.ymask = y_mask;
  a.init_h = init_h; a.init_c = init_c;
  a.h = hbuf; a.c = cbuf; a.h1 = h1buf; a.c1 = c1buf; a.qsum = qsum;
  a.attnum = attnum; a.attden = attden; a.feat8 = feat8; a.bar = bar;
  hipFuncSetAttribute(reinterpret_cast<const void*>(decoder_coop),
                      hipFuncAttributeMaxDynamicSharedMemorySize, 160448);
  decoder_coop<<<256, 256, 160448, stream>>>(a);

  hipFuncSetAttribute(reinterpret_cast<const void*>(lse_gemm_fp8),
                      hipFuncAttributeMaxDynamicSharedMemorySize, 132096);
  lse_gemm_fp8<<<782, 512, 132096, stream>>>(feat8, Wp, bp, lse);

  target_logit<<<400, 256, 0, stream>>>(feat8, Wp, bp, y_idx, tlog);
  finalize<<<1, 64, 0, stream>>>(lse, tlog, y_mask, (float*)d_out);
}

// Round 13
// 4765.627 us; speedup vs baseline: 1.7515x; 1.0600x over previous
//
#include <hip/hip_runtime.h>
#include <stdint.h>

typedef unsigned int u32;
typedef unsigned short u16;
typedef unsigned char u8;
typedef long long i64;
typedef __attribute__((ext_vector_type(4))) float f32x4;
typedef __attribute__((ext_vector_type(4))) float f32x4v;
typedef __attribute__((ext_vector_type(8))) short bf16x8;

#define T_LEN 100
#define S_LEN 400
#define NB 16
#define HD 512
#define CTXD 1024
#define VOC 50000
#define K4H 2048
#define M_ALL 1600

static __device__ __forceinline__ float bf2f(u16 v) {
  union { u32 u; float f; } c; c.u = ((u32)v) << 16; return c.f;
}
static __device__ __forceinline__ u16 f2bf(float f) {
  union { float f; u32 u; } c; c.f = f;
  return (u16)((c.u + 0x7fffu + ((c.u >> 16) & 1u)) >> 16);
}
static __device__ __forceinline__ u32 pack2(float a, float b) {
  return (u32)f2bf(a) | ((u32)f2bf(b) << 16);
}
static __device__ __forceinline__ uint4 pack8v(f32x4v a, f32x4v b) {
  return make_uint4(pack2(a.x, a.y), pack2(a.z, a.w), pack2(b.x, b.y), pack2(b.z, b.w));
}
static __device__ __forceinline__ u32 pkfp8(float x, float y, float z, float w) {
  int p = 0;
  p = __builtin_amdgcn_cvt_pk_fp8_f32(x, y, p, 0);
  p = __builtin_amdgcn_cvt_pk_fp8_f32(z, w, p, 1);
  return (u32)p;
}
static __device__ __forceinline__ float sigm(float x) { return 1.f / (1.f + __expf(-x)); }
static __device__ __forceinline__ float tanh_(float x) {
  float e = __expf(2.f * x);
  return 1.f - 2.f / (e + 1.f);
}
// coherent scalar load/store (agent scope)
static __device__ __forceinline__ float ald(const float* p) {
  return __hip_atomic_load(p, __ATOMIC_RELAXED, __HIP_MEMORY_SCOPE_AGENT);
}
static __device__ __forceinline__ void ast(float* p, float v) {
  __hip_atomic_store(p, v, __ATOMIC_RELAXED, __HIP_MEMORY_SCOPE_AGENT);
}
// coherent 16B loads, batch of 4 with one waitcnt
static __device__ __forceinline__ void cld4b(const float* p0, const float* p1,
                                             const float* p2, const float* p3,
                                             f32x4v& v0, f32x4v& v1, f32x4v& v2, f32x4v& v3) {
  asm volatile(
      "global_load_dwordx4 %0, %4, off sc0 sc1\n\t"
      "global_load_dwordx4 %1, %5, off sc0 sc1\n\t"
      "global_load_dwordx4 %2, %6, off sc0 sc1\n\t"
      "global_load_dwordx4 %3, %7, off sc0 sc1\n\t"
      "s_waitcnt vmcnt(0)"
      : "=&v"(v0), "=&v"(v1), "=&v"(v2), "=&v"(v3)
      : "v"(p0), "v"(p1), "v"(p2), "v"(p3)
      : "memory");
}
// coherent 16B loads, batch of 8
static __device__ __forceinline__ void cld8(
    const float* p0, const float* p1, const float* p2, const float* p3,
    const float* p4, const float* p5, const float* p6, const float* p7,
    f32x4v& v0, f32x4v& v1, f32x4v& v2, f32x4v& v3,
    f32x4v& v4, f32x4v& v5, f32x4v& v6, f32x4v& v7) {
  asm volatile(
      "global_load_dwordx4 %0, %8, off sc0 sc1\n\t"
      "global_load_dwordx4 %1, %9, off sc0 sc1\n\t"
      "global_load_dwordx4 %2, %10, off sc0 sc1\n\t"
      "global_load_dwordx4 %3, %11, off sc0 sc1\n\t"
      "global_load_dwordx4 %4, %12, off sc0 sc1\n\t"
      "global_load_dwordx4 %5, %13, off sc0 sc1\n\t"
      "global_load_dwordx4 %6, %14, off sc0 sc1\n\t"
      "global_load_dwordx4 %7, %15, off sc0 sc1\n\t"
      "s_waitcnt vmcnt(0)"
      : "=&v"(v0), "=&v"(v1), "=&v"(v2), "=&v"(v3),
        "=&v"(v4), "=&v"(v5), "=&v"(v6), "=&v"(v7)
      : "v"(p0), "v"(p1), "v"(p2), "v"(p3), "v"(p4), "v"(p5), "v"(p6), "v"(p7)
      : "memory");
}
static __device__ __forceinline__ void sig(u32* ctr) {
  __hip_atomic_fetch_add(ctr, 1u, __ATOMIC_RELAXED, __HIP_MEMORY_SCOPE_AGENT);
}
static __device__ __forceinline__ void waitge(u32* ctr, u32 tgt) {
  while (__hip_atomic_load(ctr, __ATOMIC_RELAXED, __HIP_MEMORY_SCOPE_AGENT) < tgt)
    __builtin_amdgcn_s_sleep(1);
}

__global__ void sentinel_kernel(float* out, float v) {
  if (threadIdx.x < NB) out[threadIdx.x] = v;
}

// ---------------- fused cast kernel ----------------
struct CastArgs {
  const float* src[9];
  u16* dst[9];
  u32 cum[10];
};

__global__ __launch_bounds__(256) void cast_all(CastArgs A) {
  u32 i = blockIdx.x * 256 + threadIdx.x;
  if (i >= A.cum[9]) return;
  int seg = 0;
  while (i >= A.cum[seg + 1]) seg++;
  u32 li = i - A.cum[seg];
  const float* s = A.src[seg];
  f32x4v a = __builtin_nontemporal_load((const f32x4v*)&s[li * 8]);
  f32x4v b = __builtin_nontemporal_load((const f32x4v*)&s[li * 8 + 4]);
  if (seg < 8) {
    *(uint4*)&A.dst[seg][li * 8] = pack8v(a, b);
  } else {  // y_emb -> feat8[:, 1536:2048] (fp8)
    u32 m = li >> 6, k8 = (li & 63) << 3;
    u8* f8 = (u8*)A.dst[8];
    uint2 t;
    t.x = pkfp8(a.x, a.y, a.z, a.w);
    t.y = pkfp8(b.x, b.y, b.z, b.w);
    *(uint2*)&f8[(size_t)m * K4H + 1536 + k8] = t;
  }
}

// ---------------- generic bf16 MFMA GEMM ----------------
template <int MODE>
__global__ __launch_bounds__(256) void gemm_bf16(const u16* __restrict__ A,
                                                 const u16* __restrict__ Bw,
                                                 void* __restrict__ out,
                                                 const float* __restrict__ bias1,
                                                 const float* __restrict__ bias2,
                                                 int M, int N, int K) {
  __shared__ u16 As[64][40];
  __shared__ u16 Bs[64][40];
  int nb = N / 64;
  int m0 = (blockIdx.x / nb) * 64;
  int n0 = (blockIdx.x % nb) * 64;
  int tid = threadIdx.x;
  int lane = tid & 63;
  int w = tid >> 6;
  int wm = (w >> 1) * 32, wn = (w & 1) * 32;
  f32x4 acc[2][2] = {};
  int arow = tid >> 2, achk = (tid & 3) * 8;
  for (int k0 = 0; k0 < K; k0 += 32) {
    __syncthreads();
    *(uint4*)&As[arow][achk] = *(const uint4*)&A[(size_t)(m0 + arow) * K + k0 + achk];
    *(uint4*)&Bs[arow][achk] = *(const uint4*)&Bw[(size_t)(n0 + arow) * K + k0 + achk];
    __syncthreads();
    int r = lane & 15, kg = lane >> 4;
    bf16x8 a0 = *(const bf16x8*)&As[wm + r][kg * 8];
    bf16x8 a1 = *(const bf16x8*)&As[wm + 16 + r][kg * 8];
    bf16x8 b0 = *(const bf16x8*)&Bs[wn + r][kg * 8];
    bf16x8 b1 = *(const bf16x8*)&Bs[wn + 16 + r][kg * 8];
    acc[0][0] = __builtin_amdgcn_mfma_f32_16x16x32_bf16(a0, b0, acc[0][0], 0, 0, 0);
    acc[0][1] = __builtin_amdgcn_mfma_f32_16x16x32_bf16(a0, b1, acc[0][1], 0, 0, 0);
    acc[1][0] = __builtin_amdgcn_mfma_f32_16x16x32_bf16(a1, b0, acc[1][0], 0, 0, 0);
    acc[1][1] = __builtin_amdgcn_mfma_f32_16x16x32_bf16(a1, b1, acc[1][1], 0, 0, 0);
  }
  int col = lane & 15, rg = lane >> 4;
#pragma unroll
  for (int fi = 0; fi < 2; fi++)
#pragma unroll
    for (int fj = 0; fj < 2; fj++)
#pragma unroll
      for (int r = 0; r < 4; r++) {
        int m = m0 + wm + fi * 16 + rg * 4 + r;
        int n = n0 + wn + fj * 16 + col;
        float v = acc[fi][fj][r] + bias1[n];
        if constexpr (MODE == 1) {
          v += bias2[n];
          ((float*)out)[(size_t)m * N + n] = v;
        } else {
          ((u16*)out)[(size_t)m * N + n] = f2bf(v);
        }
      }
}

// ---------------- persistent decoder (512 threads = 2 waves/SIMD) ----------------
struct DecArgs {
  const u16 *pctx, *ctx, *Whh, *Wcomb, *Uxw, *Wxw;
  const float *xW, *bx, *uatt, *xmask, *ymask, *init_h, *init_c;
  float *h, *c, *h1, *c1, *qsum, *attnum, *attden;
  u8* feat8;
  u32* bar;
};

// Dynamic LDS (bytes), total 160,448:
//   [0,      51200)  pctx_l  u16[25*1024]   (persistent)
//   [51200, 102400)  ctx_l   u16[25*1024]   (persistent)
//   [102400,106496)  ua_l    f32[1024]      (persistent)
//   [106496,106624)  xm_l    f32[32]        (persistent)
//   [106624,160448)  phase union (53824 B):
//     A: Al u16[16*520] @0 | gbA f32[2][4][16][32] @16640 | h1c1 u16[16*72] @33024
//     C: q_l f32[1024] @0 | p_l f32[32] @4096
//     D: AlD u16[16*1544] @0 | gbD f32[4][16][16] @49408 | attden_l f32[16] @53504
__global__ __launch_bounds__(512, 1) void decoder_coop(DecArgs A) {
  extern __shared__ char smem[];
  u16* pctx_l = (u16*)smem;
  u16* ctx_l = (u16*)(smem + 51200);
  float* ua_l = (float*)(smem + 102400);
  float* xm_l = (float*)(smem + 106496);
  char* un = smem + 106624;

  const int tid = threadIdx.x;
  const int blk = blockIdx.x;
  const int lane = tid & 63, w = tid >> 6;  // w 0..7
  const int g = w & 3, hv = w >> 2;
  const int r16 = lane & 15, kg = lane >> 4;
  const int bK = blk & 15;
  const int s0 = (blk >> 4) * 25;
  u32* qdone = A.bar;
  u32* cdone = A.bar + 64;
  u32* h2done = A.bar + 128;

  // ---- one-time prefill of persistent LDS ----
  for (int idx = tid; idx < 25 * 128; idx += 512) {
    int i = idx >> 7, c8 = (idx & 127) << 3;
    *(uint4*)&pctx_l[i * 1024 + c8] =
        *(const uint4*)&A.pctx[((size_t)(s0 + i) * NB + bK) * CTXD + c8];
    *(uint4*)&ctx_l[i * 1024 + c8] =
        *(const uint4*)&A.ctx[((size_t)(s0 + i) * NB + bK) * CTXD + c8];
  }
  {
    int c0 = tid * 2;
    ua_l[c0] = A.uatt[c0];
    ua_l[c0 + 1] = A.uatt[c0 + 1];
  }
  if (tid < 25) xm_l[tid] = A.xmask[(s0 + tid) * NB + bK];
  __syncthreads();
  // hoist u_att columns for this lane into registers (fixed across steps/rows)
  float uav[16];
  {
    const float* ub = &ua_l[lane * 16];
    *(f32x4*)&uav[0] = *(const f32x4*)&ub[0];
    *(f32x4*)&uav[4] = *(const f32x4*)&ub[4];
    *(f32x4*)&uav[8] = *(const f32x4*)&ub[8];
    *(f32x4*)&uav[12] = *(const f32x4*)&ub[12];
  }

  for (int ts = 0; ts < T_LEN; ts++) {
    const int par = ts & 1;
    // ========= phase A: LSTM1 + q partials -> qsum (blocks 0..15) =========
    if (blk < 16) {
      if (tid == 0) waitge(h2done, 32u * (u32)ts);
      __syncthreads();
      u16* Al = (u16*)un;
      float* gbA = (float*)(un + 16640);  // [2][4][16][32]
      u16* h1c1 = (u16*)(un + 33024);
      const float* hs = ts ? A.h : A.init_h;
      const float* cs = ts ? A.c : A.init_c;
      {
        int b = tid >> 5, k16 = (tid & 31) << 4;
        const float* src = &hs[b * 512 + k16];
        f32x4v v0, v1, v2, v3;
        cld4b(src, src + 4, src + 8, src + 12, v0, v1, v2, v3);
        *(uint4*)&Al[b * 520 + k16] = pack8v(v0, v1);
        *(uint4*)&Al[b * 520 + k16 + 8] = pack8v(v2, v3);
      }
      __syncthreads();
      const int j0 = blk * 32;
      {
        f32x4 acc0 = {}, acc1 = {};
        const size_t row0 = (size_t)(g * 512 + j0 + r16) * 512;
        const size_t row1 = (size_t)(g * 512 + j0 + 16 + r16) * 512;
        const int ksb = hv * 8;
#pragma unroll
        for (int ks = 0; ks < 8; ks++) {
          int kk = (ksb + ks) * 32 + kg * 8;
          bf16x8 a = *(const bf16x8*)&Al[r16 * 520 + kk];
          bf16x8 b0 = *(const bf16x8*)&A.Whh[row0 + kk];
          bf16x8 b1 = *(const bf16x8*)&A.Whh[row1 + kk];
          acc0 = __builtin_amdgcn_mfma_f32_16x16x32_bf16(a, b0, acc0, 0, 0, 0);
          acc1 = __builtin_amdgcn_mfma_f32_16x16x32_bf16(a, b1, acc1, 0, 0, 0);
        }
        float* gb = &gbA[((hv * 4 + g) * 16) * 32];
#pragma unroll
        for (int r = 0; r < 4; r++) {
          gb[(kg * 4 + r) * 32 + r16] = acc0[r];
          gb[(kg * 4 + r) * 32 + 16 + r16] = acc1[r];
        }
      }
      __syncthreads();
      {
        int b = tid >> 5, j = tid & 31;
        int n = j0 + j;
        const float* xw = &A.xW[(size_t)(ts * NB + b) * K4H];
#define GBA(hh, gg) gbA[(((hh)*4 + (gg)) * 16 + b) * 32 + j]
        float gi = GBA(0, 0) + GBA(1, 0) + xw[n];
        float gf = GBA(0, 1) + GBA(1, 1) + xw[512 + n];
        float gg2 = GBA(0, 2) + GBA(1, 2) + xw[1024 + n];
        float go = GBA(0, 3) + GBA(1, 3) + xw[1536 + n];
#undef GBA
        float ymv = A.ymask[ts * NB + b];
        float c_old = ald(&cs[b * 512 + n]);
        float h_old = ald(&hs[b * 512 + n]);
        float c1v = sigm(gf) * c_old + sigm(gi) * tanh_(gg2);
        float h1v = sigm(go) * tanh_(c1v);
        h1v = ymv * h1v + (1.f - ymv) * h_old;
        c1v = ymv * c1v + (1.f - ymv) * c_old;
        ast(&A.h1[b * 512 + n], h1v);
        ast(&A.c1[b * 512 + n], c1v);
        h1c1[b * 72 + j] = f2bf(h1v);
        h1c1[b * 72 + 32 + j] = f2bf(c1v);
      }
      __syncthreads();
      {
        bf16x8 a0 = *(const bf16x8*)&h1c1[r16 * 72 + kg * 8];
        bf16x8 a1 = *(const bf16x8*)&h1c1[r16 * 72 + 32 + kg * 8];
        float* qs = A.qsum + par * 16384;
        for (int nt = w; nt < 64; nt += 8) {
          int n = nt * 16 + r16;
          bf16x8 b0 = *(const bf16x8*)&A.Wcomb[(size_t)n * 1024 + j0 + kg * 8];
          bf16x8 b1 = *(const bf16x8*)&A.Wcomb[(size_t)n * 1024 + 512 + j0 + kg * 8];
          f32x4 acc = {};
          acc = __builtin_amdgcn_mfma_f32_16x16x32_bf16(a0, b0, acc, 0, 0, 0);
          acc = __builtin_amdgcn_mfma_f32_16x16x32_bf16(a1, b1, acc, 0, 0, 0);
#pragma unroll
          for (int r = 0; r < 4; r++)
            atomicAdd(&qs[(kg * 4 + r) * 1024 + nt * 16 + r16], acc[r]);
        }
      }
      __syncthreads();
      if (tid == 0) sig(qdone);
    }
    // ========= phase C: attention (all 256 blocks) =========
    {
      if (tid == 0) waitge(qdone, 16u * (u32)(ts + 1));
      __syncthreads();
      float* q_l = (float*)un;
      float* p_l = (float*)(un + 4096);
      {
        int c0 = tid * 2;
        const float* qs = &A.qsum[par * 16384 + bK * 1024 + c0];
        q_l[c0] = ald(qs);
        q_l[c0 + 1] = ald(qs + 1);
      }
      __syncthreads();
      // lane-fixed q columns into registers
      float qv[16];
      {
        const float* qb = &q_l[lane * 16];
        *(f32x4*)&qv[0] = *(const f32x4*)&qb[0];
        *(f32x4*)&qv[4] = *(const f32x4*)&qb[4];
        *(f32x4*)&qv[8] = *(const f32x4*)&qb[8];
        *(f32x4*)&qv[12] = *(const f32x4*)&qb[12];
      }
      for (int i = w; i < 25; i += 8) {
        const u16* prow = &pctx_l[i * 1024 + lane * 16];
        bf16x8 pv0 = *(const bf16x8*)&prow[0];
        bf16x8 pv1 = *(const bf16x8*)&prow[8];
        float s = 0.f;
#pragma unroll
        for (int e = 0; e < 8; e++) s += tanh_(bf2f((u16)pv0[e]) + qv[e]) * uav[e];
#pragma unroll
        for (int e = 0; e < 8; e++) s += tanh_(bf2f((u16)pv1[e]) + qv[8 + e]) * uav[8 + e];
#pragma unroll
        for (int off = 1; off < 64; off <<= 1) s += __shfl_xor(s, off);
        if (lane == 0) {
          float xm = xm_l[i];
          p_l[i] = __expf(s * xm) * xm;
        }
      }
      __syncthreads();
      const int c2 = tid << 1;
      float n0 = 0, n1 = 0;
#pragma unroll 5
      for (int i = 0; i < 25; i++) {
        float pv = p_l[i];
        u32 ld = *(const u32*)&ctx_l[i * 1024 + c2];
        n0 += pv * bf2f((u16)(ld & 0xffff));
        n1 += pv * bf2f((u16)(ld >> 16));
      }
      float* dst = &A.attnum[par * 16384 + bK * 1024 + c2];
      atomicAdd(dst + 0, n0);
      atomicAdd(dst + 1, n1);
      if (tid == 0) {
        float d = 0.f;
        for (int i = 0; i < 25; i++) d += p_l[i];
        atomicAdd(&A.attden[par * NB + bK], d);
      }
      __syncthreads();
      if (tid == 0) sig(cdone);
    }
    // ========= phase D: gates2 + state update (blocks 0..31) =========
    if (blk < 32) {
      if (tid == 0) waitge(cdone, 256u * (u32)(ts + 1));
      __syncthreads();
      u16* AlD = (u16*)un;
      float* gbD = (float*)(un + 49408);      // [4][16][16] (atomic-accumulated)
      float* attden_l = (float*)(un + 53504); // [16]
      if (tid < NB) attden_l[tid] = ald(&A.attden[par * NB + tid]);
      gbD[tid] = 0.f;
      gbD[tid + 512] = 0.f;
      {
        int b = tid >> 5, k16 = (tid & 31) << 4;
        const float* src = &A.h1[b * 512 + k16];
        f32x4v v0, v1, v2, v3;
        cld4b(src, src + 4, src + 8, src + 12, v0, v1, v2, v3);
        *(uint4*)&AlD[b * 1544 + k16] = pack8v(v0, v1);
        *(uint4*)&AlD[b * 1544 + k16 + 8] = pack8v(v2, v3);
      }
      __syncthreads();
      {
        const float* base = &A.attnum[par * 16384];
        const int rh = tid >> 8, c4 = (tid & 255) << 2;
        const int r0 = rh * 8;
        f32x4v a0, a1, a2, a3, a4, a5, a6, a7;
        cld8(base + (r0 + 0) * 1024 + c4, base + (r0 + 1) * 1024 + c4,
             base + (r0 + 2) * 1024 + c4, base + (r0 + 3) * 1024 + c4,
             base + (r0 + 4) * 1024 + c4, base + (r0 + 5) * 1024 + c4,
             base + (r0 + 6) * 1024 + c4, base + (r0 + 7) * 1024 + c4,
             a0, a1, a2, a3, a4, a5, a6, a7);
#define ATT_ST(i, vv)                                                        \
  {                                                                          \
    float rd = 1.f / attden_l[i];                                            \
    uint2 t;                                                                 \
    t.x = pack2(vv.x * rd, vv.y * rd);                                       \
    t.y = pack2(vv.z * rd, vv.w * rd);                                       \
    *(uint2*)&AlD[(i) * 1544 + 512 + c4] = t;                                \
  }
        ATT_ST(r0 + 0, a0) ATT_ST(r0 + 1, a1) ATT_ST(r0 + 2, a2) ATT_ST(r0 + 3, a3)
        ATT_ST(r0 + 4, a4) ATT_ST(r0 + 5, a5) ATT_ST(r0 + 6, a6) ATT_ST(r0 + 7, a7)
#undef ATT_ST
      }
      __syncthreads();
      if (blk < 16 && tid < 256) {
        const u16* arow = &AlD[blk * 1544 + 512];
        int c4 = tid * 4;
        u32 p = pkfp8(bf2f(arow[c4]), bf2f(arow[c4 + 1]), bf2f(arow[c4 + 2]),
                      bf2f(arow[c4 + 3]));
        *(u32*)&A.feat8[(size_t)(ts * NB + blk) * K4H + 512 + c4] = p;
      }
      const int j0 = blk * 16;
      {
        f32x4 acc = {};
        const size_t rowU = (size_t)(g * 512 + j0 + r16) * 512;
        const size_t rowW = (size_t)(g * 512 + j0 + r16) * 1024;
        if (hv == 0) {
#pragma unroll
          for (int ks = 0; ks < 16; ks++) {
            int kk = ks * 32 + kg * 8;
            bf16x8 a = *(const bf16x8*)&AlD[r16 * 1544 + kk];
            bf16x8 b0 = *(const bf16x8*)&A.Uxw[rowU + kk];
            acc = __builtin_amdgcn_mfma_f32_16x16x32_bf16(a, b0, acc, 0, 0, 0);
          }
#pragma unroll
          for (int ks = 16; ks < 24; ks++) {
            bf16x8 a = *(const bf16x8*)&AlD[r16 * 1544 + ks * 32 + kg * 8];
            bf16x8 b0 = *(const bf16x8*)&A.Wxw[rowW + (ks - 16) * 32 + kg * 8];
            acc = __builtin_amdgcn_mfma_f32_16x16x32_bf16(a, b0, acc, 0, 0, 0);
          }
        } else {
#pragma unroll
          for (int ks = 24; ks < 48; ks++) {
            bf16x8 a = *(const bf16x8*)&AlD[r16 * 1544 + ks * 32 + kg * 8];
            bf16x8 b0 = *(const bf16x8*)&A.Wxw[rowW + (ks - 16) * 32 + kg * 8];
            acc = __builtin_amdgcn_mfma_f32_16x16x32_bf16(a, b0, acc, 0, 0, 0);
          }
        }
#pragma unroll
        for (int r = 0; r < 4; r++)
          atomicAdd(&gbD[(g * 16 + kg * 4 + r) * 16 + r16], acc[r]);
      }
      __syncthreads();
      if (tid < 256) {
        int b = tid >> 4, j = tid & 15;
        int n = j0 + j;
        float xi = gbD[(0 * 16 + b) * 16 + j] + A.bx[n];
        float xf = gbD[(1 * 16 + b) * 16 + j] + A.bx[512 + n];
        float xo = gbD[(2 * 16 + b) * 16 + j] + A.bx[1024 + n];
        float xc = gbD[(3 * 16 + b) * 16 + j] + A.bx[1536 + n];
        float ymv = A.ymask[ts * NB + b];
        float c1v = ald(&A.c1[b * 512 + n]);
        float h1v = ald(&A.h1[b * 512 + n]);
        float c2 = sigm(xf) * c1v + sigm(xi) * tanh_(xc);
        float h2 = sigm(xo) * tanh_(c2);
        c2 = ymv * c2 + (1.f - ymv) * c1v;
        h2 = ymv * h2 + (1.f - ymv) * h1v;
        ast(&A.h[b * 512 + n], h2);
        ast(&A.c[b * 512 + n], c2);
        int p8 = 0;
        p8 = __builtin_amdgcn_cvt_pk_fp8_f32(h2, h2, p8, 0);
        A.feat8[(size_t)(ts * NB + b) * K4H + n] = (u8)(p8 & 0xff);
      }
      // zero consumed-parity buffers for future steps
      ast(&A.attnum[(par ^ 1) * 16384 + blk * 512 + tid], 0.f);
      ast(&A.qsum[par * 16384 + blk * 512 + tid], 0.f);
      if (blk == 0 && tid < NB) ast(&A.attden[(par ^ 1) * NB + tid], 0.f);
      __syncthreads();
      if (tid == 0) sig(h2done);
    }
  }
}

// ---------------- fused vocab GEMM (fp8) + sum(exp) ----------------
__global__ __launch_bounds__(512, 1) void lse_gemm_fp8(const u8* __restrict__ feat8,
                                                       const float* __restrict__ Wp,
                                                       const float* __restrict__ bp,
                                                       float* __restrict__ lse) {
  extern __shared__ char smem[];
  u8* Bl = (u8*)smem;  // [64][2064] fp8
  const int tid = threadIdx.x;
  const int n0 = blockIdx.x * 64;
  for (int n = 0; n < 64; n++) {
    int gn = n0 + n;
    f32x4v f = {0.f, 0.f, 0.f, 0.f};
    if (gn < VOC)
      f = __builtin_nontemporal_load((const f32x4v*)&Wp[(size_t)gn * K4H + tid * 4]);
    *(u32*)&Bl[n * 2064 + tid * 4] = pkfp8(f.x, f.y, f.z, f.w);
  }
  __syncthreads();
  const int w = tid >> 6, lane = tid & 63;
  const int r16 = lane & 15, kg = lane >> 4;
  bool vj[4];
  float bpj[4];
#pragma unroll
  for (int j = 0; j < 4; j++) {
    int nf = n0 + j * 16 + r16;
    vj[j] = nf < VOC;
    bpj[j] = vj[j] ? bp[nf] : 0.f;
  }
  for (int qq = w; qq < 25; qq += 8) {
    int mrow = qq * 64;
    f32x4 acc[4][4] = {};
    for (int ks = 0; ks < 64; ks++) {
      i64 b0 = *(const i64*)&Bl[(r16) * 2064 + ks * 32 + kg * 8];
      i64 b1 = *(const i64*)&Bl[(16 + r16) * 2064 + ks * 32 + kg * 8];
      i64 b2 = *(const i64*)&Bl[(32 + r16) * 2064 + ks * 32 + kg * 8];
      i64 b3 = *(const i64*)&Bl[(48 + r16) * 2064 + ks * 32 + kg * 8];
#pragma unroll
      for (int s = 0; s < 4; s++) {
        i64 a = *(const i64*)&feat8[(size_t)(mrow + s * 16 + r16) * K4H + ks * 32 + kg * 8];
        acc[s][0] = __builtin_amdgcn_mfma_f32_16x16x32_fp8_fp8(a, b0, acc[s][0], 0, 0, 0);
        acc[s][1] = __builtin_amdgcn_mfma_f32_16x16x32_fp8_fp8(a, b1, acc[s][1], 0, 0, 0);
        acc[s][2] = __builtin_amdgcn_mfma_f32_16x16x32_fp8_fp8(a, b2, acc[s][2], 0, 0, 0);
        acc[s][3] = __builtin_amdgcn_mfma_f32_16x16x32_fp8_fp8(a, b3, acc[s][3], 0, 0, 0);
      }
    }
#pragma unroll
    for (int s = 0; s < 4; s++) {
#pragma unroll
      for (int r = 0; r < 4; r++) {
        float e = 0.f;
#pragma unroll
        for (int j = 0; j < 4; j++)
          if (vj[j]) e += __expf(acc[s][j][r] + bpj[j]);
        e += __shfl_xor(e, 1);
        e += __shfl_xor(e, 2);
        e += __shfl_xor(e, 4);
        e += __shfl_xor(e, 8);
        if (r16 == 0) atomicAdd(&lse[mrow + s * 16 + kg * 4 + r], e);
      }
    }
  }
}

// ---------------- target logit ----------------
__global__ __launch_bounds__(256) void target_logit(const u8* __restrict__ feat8,
                                                    const float* __restrict__ Wp,
                                                    const float* __restrict__ bp,
                                                    const int* __restrict__ yidx,
                                                    float* __restrict__ tlog) {
  int gw = (blockIdx.x * 256 + threadIdx.x) >> 6;
  int lane = threadIdx.x & 63;
  if (gw >= M_ALL) return;
  int yi = yidx[gw];
  const float* wrow = Wp + (size_t)yi * K4H;
  const u8* frow = feat8 + (size_t)gw * K4H;
  float s = 0.f;
#pragma unroll
  for (int i = 0; i < 4; i++) {
    int k = i * 512 + lane * 8;
    uint2 fv = *(const uint2*)&frow[k];
    f32x4v w0 = __builtin_nontemporal_load((const f32x4v*)&wrow[k]);
    f32x4v w1 = __builtin_nontemporal_load((const f32x4v*)&wrow[k + 4]);
    s += __builtin_amdgcn_cvt_f32_fp8(fv.x, 0) * w0.x;
    s += __builtin_amdgcn_cvt_f32_fp8(fv.x, 1) * w0.y;
    s += __builtin_amdgcn_cvt_f32_fp8(fv.x, 2) * w0.z;
    s += __builtin_amdgcn_cvt_f32_fp8(fv.x, 3) * w0.w;
    s += __builtin_amdgcn_cvt_f32_fp8(fv.y, 0) * w1.x;
    s += __builtin_amdgcn_cvt_f32_fp8(fv.y, 1) * w1.y;
    s += __builtin_amdgcn_cvt_f32_fp8(fv.y, 2) * w1.z;
    s += __builtin_amdgcn_cvt_f32_fp8(fv.y, 3) * w1.w;
  }
#pragma unroll
  for (int off = 1; off < 64; off <<= 1) s += __shfl_xor(s, off);
  if (lane == 0) tlog[gw] = s + bp[yi];
}

__global__ void finalize(const float* __restrict__ lse, const float* __restrict__ tlog,
                         const float* __restrict__ ymask, float* __restrict__ out) {
  int b = threadIdx.x;
  if (b < NB) {
    float sc = 0.f, sm = 0.f;
    for (int t = 0; t < T_LEN; t++) {
      int m = t * NB + b;
      float ym = ymask[m];
      sc += (logf(lse[m]) - tlog[m]) * ym;
      sm += ym;
    }
    out[b] = sc / sm;
  }
}

// ---------------- host launcher ----------------
extern "C" void kernel_launch(void* const* d_in, const int* in_sizes, int n_in,
                              void* d_out, int out_size, void* d_ws, size_t ws_size,
                              hipStream_t stream) {
  const float* y_emb = (const float*)d_in[0];
  const float* context = (const float*)d_in[1];
  const float* init_h = (const float*)d_in[2];
  const float* init_c = (const float*)d_in[3];
  const float* x_mask = (const float*)d_in[4];
  const float* y_mask = (const float*)d_in[5];
  const int* y_idx = (const int*)d_in[6];
  const float* W_ih = (const float*)d_in[7];
  const float* W_hh = (const float*)d_in[8];
  const float* b_ih = (const float*)d_in[9];
  const float* b_hh = (const float*)d_in[10];
  const float* Wx = (const float*)d_in[11];
  const float* Ux = (const float*)d_in[12];
  const float* bx = (const float*)d_in[13];
  const float* Wc_att = (const float*)d_in[14];
  const float* b_att = (const float*)d_in[15];
  const float* W_comb = (const float*)d_in[16];
  const float* U_att = (const float*)d_in[17];
  const float* Wp = (const float*)d_in[18];
  const float* bp = (const float*)d_in[19];

  if (ws_size < 60000000ULL) {
    sentinel_kernel<<<1, 64, 0, stream>>>((float*)d_out, (float)(ws_size >> 20));
    return;
  }

  // ---- workspace layout (bytes), end 59,342,848 ----
  char* ws = (char*)d_ws;
  float* lse = (float*)(ws + 0);
  float* attnum = (float*)(ws + 8192);
  float* attden = (float*)(ws + 139264);
  u32* bar = (u32*)(ws + 139392);
  float* qsum = (float*)(ws + 151680);
  float* tlog = (float*)(ws + 282752);
  u16* pctx = (u16*)(ws + 294912);
  u16* ctxb = (u16*)(ws + 13402112);
  u16* Wcb = (u16*)(ws + 26509312);
  u16* yembb = (u16*)(ws + 28606464);
  u16* Wihb = (u16*)(ws + 30244864);
  u16* Whhb = (u16*)(ws + 32342016);
  u16* Wcombb = (u16*)(ws + 34439168);
  u16* Uxb = (u16*)(ws + 36536320);
  u16* Wxb = (u16*)(ws + 38633472);
  float* xW = (float*)(ws + 42827776);
  u8* feat8 = (u8*)(ws + 55934976);
  float* hbuf = (float*)(ws + 59211776);
  float* cbuf = (float*)(ws + 59244544);
  float* h1buf = (float*)(ws + 59277312);
  float* c1buf = (float*)(ws + 59310080);

  hipMemsetAsync(ws, 0, 282752, stream);

  CastArgs ca;
  ca.src[0] = context;  ca.dst[0] = ctxb;
  ca.src[1] = Wc_att;   ca.dst[1] = Wcb;
  ca.src[2] = y_emb;    ca.dst[2] = yembb;
  ca.src[3] = W_ih;     ca.dst[3] = Wihb;
  ca.src[4] = W_hh;     ca.dst[4] = Whhb;
  ca.src[5] = W_comb;   ca.dst[5] = Wcombb;
  ca.src[6] = Ux;       ca.dst[6] = Uxb;
  ca.src[7] = Wx;       ca.dst[7] = Wxb;
  ca.src[8] = y_emb;    ca.dst[8] = (u16*)feat8;
  u32 sz[9] = {819200, 131072, 102400, 131072, 131072, 131072, 131072, 262144, 102400};
  ca.cum[0] = 0;
  for (int i = 0; i < 9; i++) ca.cum[i + 1] = ca.cum[i] + sz[i];
  cast_all<<<(ca.cum[9] + 255) / 256, 256, 0, stream>>>(ca);

  gemm_bf16<0><<<1600, 256, 0, stream>>>(ctxb, Wcb, pctx, b_att, b_att, 6400, 1024, 1024);
  gemm_bf16<1><<<800, 256, 0, stream>>>(yembb, Wihb, xW, b_ih, b_hh, 1600, 2048, 512);

  DecArgs a;
  a.pctx = pctx; a.ctx = ctxb; a.Whh = Whhb; a.Wcomb = Wcombb; a.Uxw = Uxb; a.Wxw = Wxb;
  a.xW = xW; a.bx = bx; a.uatt = U_att; a.xmask = x_mask; a.ymask = y_mask;
  a.init_h = init_h; a.init_c = init_c;
  a.h = hbuf; a.c = cbuf; a.h1 = h1buf; a.c1 = c1buf; a.qsum = qsum;
  a.attnum = attnum; a.attden = attden; a.feat8 = feat8; a.bar = bar;
  hipFuncSetAttribute(reinterpret_cast<const void*>(decoder_coop),
                      hipFuncAttributeMaxDynamicSharedMemorySize, 160448);
  decoder_coop<<<256, 512, 160448, stream>>>(a);

  hipFuncSetAttribute(reinterpret_cast<const void*>(lse_gemm_fp8),
                      hipFuncAttributeMaxDynamicSharedMemorySize, 132096);
  lse_gemm_fp8<<<782, 512, 132096, stream>>>(feat8, Wp, bp, lse);

  target_logit<<<400, 256, 0, stream>>>(feat8, Wp, bp, y_idx, tlog);
  finalize<<<1, 64, 0, stream>>>(lse, tlog, y_mask, (float*)d_out);
}

// Round 15
// 4686.246 us; speedup vs baseline: 1.7811x; 1.0169x over previous
//
#include <hip/hip_runtime.h>
#include <stdint.h>

typedef unsigned int u32;
typedef unsigned short u16;
typedef unsigned char u8;
typedef long long i64;
typedef __attribute__((ext_vector_type(4))) float f32x4;
typedef __attribute__((ext_vector_type(4))) float f32x4v;
typedef __attribute__((ext_vector_type(2))) float f32x2v;
typedef __attribute__((ext_vector_type(8))) short bf16x8;

#define T_LEN 100
#define S_LEN 400
#define NB 16
#define HD 512
#define CTXD 1024
#define VOC 50000
#define K4H 2048
#define M_ALL 1600

static __device__ __forceinline__ float bf2f(u16 v) {
  union { u32 u; float f; } c; c.u = ((u32)v) << 16; return c.f;
}
static __device__ __forceinline__ u16 f2bf(float f) {
  union { float f; u32 u; } c; c.f = f;
  return (u16)((c.u + 0x7fffu + ((c.u >> 16) & 1u)) >> 16);
}
static __device__ __forceinline__ u32 pack2(float a, float b) {
  return (u32)f2bf(a) | ((u32)f2bf(b) << 16);
}
static __device__ __forceinline__ uint4 pack8v(f32x4v a, f32x4v b) {
  return make_uint4(pack2(a.x, a.y), pack2(a.z, a.w), pack2(b.x, b.y), pack2(b.z, b.w));
}
static __device__ __forceinline__ u32 pkfp8(float x, float y, float z, float w) {
  int p = 0;
  p = __builtin_amdgcn_cvt_pk_fp8_f32(x, y, p, 0);
  p = __builtin_amdgcn_cvt_pk_fp8_f32(z, w, p, 1);
  return (u32)p;
}
static __device__ __forceinline__ float sigm(float x) { return 1.f / (1.f + __expf(-x)); }
static __device__ __forceinline__ float tanh_(float x) {
  float e = __expf(2.f * x);
  return 1.f - 2.f / (e + 1.f);
}
static __device__ __forceinline__ void ast(float* p, float v) {
  __hip_atomic_store(p, v, __ATOMIC_RELAXED, __HIP_MEMORY_SCOPE_AGENT);
}
static __device__ __forceinline__ float ald(const float* p) {
  return __hip_atomic_load(p, __ATOMIC_RELAXED, __HIP_MEMORY_SCOPE_AGENT);
}
// phase A batched coherent load: 4x dwordx4 (h row) + h_old + c_old + 4 xW scalars
static __device__ __forceinline__ void cldA(
    const float* ph0, const float* ph1, const float* ph2, const float* ph3,
    const float* pho, const float* pco,
    const float* px0, const float* px1, const float* px2, const float* px3,
    f32x4v& v0, f32x4v& v1, f32x4v& v2, f32x4v& v3,
    float& ho, float& co, float& x0, float& x1, float& x2, float& x3) {
  asm volatile(
      "global_load_dwordx4 %0, %10, off sc0 sc1\n\t"
      "global_load_dwordx4 %1, %11, off sc0 sc1\n\t"
      "global_load_dwordx4 %2, %12, off sc0 sc1\n\t"
      "global_load_dwordx4 %3, %13, off sc0 sc1\n\t"
      "global_load_dword %4, %14, off sc0 sc1\n\t"
      "global_load_dword %5, %15, off sc0 sc1\n\t"
      "global_load_dword %6, %16, off sc0 sc1\n\t"
      "global_load_dword %7, %17, off sc0 sc1\n\t"
      "global_load_dword %8, %18, off sc0 sc1\n\t"
      "global_load_dword %9, %19, off sc0 sc1\n\t"
      "s_waitcnt vmcnt(0)"
      : "=&v"(v0), "=&v"(v1), "=&v"(v2), "=&v"(v3), "=&v"(ho), "=&v"(co),
        "=&v"(x0), "=&v"(x1), "=&v"(x2), "=&v"(x3)
      : "v"(ph0), "v"(ph1), "v"(ph2), "v"(ph3), "v"(pho), "v"(pco),
        "v"(px0), "v"(px1), "v"(px2), "v"(px3)
      : "memory");
}
// phase D batched coherent load: 4x dwordx4 (h1 row) + 8x dwordx4 (attnum) + c1,h1 scalars
static __device__ __forceinline__ void cldD(
    const float* ph0, const float* ph1, const float* ph2, const float* ph3,
    const float* pa0, const float* pa1, const float* pa2, const float* pa3,
    const float* pa4, const float* pa5, const float* pa6, const float* pa7,
    const float* pc1, const float* ph1s,
    f32x4v& v0, f32x4v& v1, f32x4v& v2, f32x4v& v3,
    f32x4v& a0, f32x4v& a1, f32x4v& a2, f32x4v& a3,
    f32x4v& a4, f32x4v& a5, f32x4v& a6, f32x4v& a7,
    float& c1v, float& h1v) {
  asm volatile(
      "global_load_dwordx4 %0, %14, off sc0 sc1\n\t"
      "global_load_dwordx4 %1, %15, off sc0 sc1\n\t"
      "global_load_dwordx4 %2, %16, off sc0 sc1\n\t"
      "global_load_dwordx4 %3, %17, off sc0 sc1\n\t"
      "global_load_dwordx4 %4, %18, off sc0 sc1\n\t"
      "global_load_dwordx4 %5, %19, off sc0 sc1\n\t"
      "global_load_dwordx4 %6, %20, off sc0 sc1\n\t"
      "global_load_dwordx4 %7, %21, off sc0 sc1\n\t"
      "global_load_dwordx4 %8, %22, off sc0 sc1\n\t"
      "global_load_dwordx4 %9, %23, off sc0 sc1\n\t"
      "global_load_dwordx4 %10, %24, off sc0 sc1\n\t"
      "global_load_dwordx4 %11, %25, off sc0 sc1\n\t"
      "global_load_dword %12, %26, off sc0 sc1\n\t"
      "global_load_dword %13, %27, off sc0 sc1\n\t"
      "s_waitcnt vmcnt(0)"
      : "=&v"(v0), "=&v"(v1), "=&v"(v2), "=&v"(v3),
        "=&v"(a0), "=&v"(a1), "=&v"(a2), "=&v"(a3),
        "=&v"(a4), "=&v"(a5), "=&v"(a6), "=&v"(a7),
        "=&v"(c1v), "=&v"(h1v)
      : "v"(ph0), "v"(ph1), "v"(ph2), "v"(ph3),
        "v"(pa0), "v"(pa1), "v"(pa2), "v"(pa3),
        "v"(pa4), "v"(pa5), "v"(pa6), "v"(pa7),
        "v"(pc1), "v"(ph1s)
      : "memory");
}
// phase C: one coherent dwordx2 (destination must be an aligned VGPR pair)
static __device__ __forceinline__ f32x2v cldC(const float* p) {
  f32x2v v;
  asm volatile(
      "global_load_dwordx2 %0, %1, off sc0 sc1\n\t"
      "s_waitcnt vmcnt(0)"
      : "=&v"(v) : "v"(p) : "memory");
  return v;
}
static __device__ __forceinline__ void sig(u32* ctr) {
  __hip_atomic_fetch_add(ctr, 1u, __ATOMIC_RELAXED, __HIP_MEMORY_SCOPE_AGENT);
}
static __device__ __forceinline__ void waitge(u32* ctr, u32 tgt) {
  while (__hip_atomic_load(ctr, __ATOMIC_RELAXED, __HIP_MEMORY_SCOPE_AGENT) < tgt)
    __builtin_amdgcn_s_sleep(1);
}

__global__ void sentinel_kernel(float* out, float v) {
  if (threadIdx.x < NB) out[threadIdx.x] = v;
}

// ---------------- fused cast kernel ----------------
struct CastArgs {
  const float* src[9];
  u16* dst[9];
  u32 cum[10];
};

__global__ __launch_bounds__(256) void cast_all(CastArgs A) {
  u32 i = blockIdx.x * 256 + threadIdx.x;
  if (i >= A.cum[9]) return;
  int seg = 0;
  while (i >= A.cum[seg + 1]) seg++;
  u32 li = i - A.cum[seg];
  const float* s = A.src[seg];
  f32x4v a = __builtin_nontemporal_load((const f32x4v*)&s[li * 8]);
  f32x4v b = __builtin_nontemporal_load((const f32x4v*)&s[li * 8 + 4]);
  if (seg < 8) {
    *(uint4*)&A.dst[seg][li * 8] = pack8v(a, b);
  } else {  // y_emb -> feat8[:, 1536:2048] (fp8)
    u32 m = li >> 6, k8 = (li & 63) << 3;
    u8* f8 = (u8*)A.dst[8];
    uint2 t;
    t.x = pkfp8(a.x, a.y, a.z, a.w);
    t.y = pkfp8(b.x, b.y, b.z, b.w);
    *(uint2*)&f8[(size_t)m * K4H + 1536 + k8] = t;
  }
}

// ---------------- generic bf16 MFMA GEMM ----------------
template <int MODE>
__global__ __launch_bounds__(256) void gemm_bf16(const u16* __restrict__ A,
                                                 const u16* __restrict__ Bw,
                                                 void* __restrict__ out,
                                                 const float* __restrict__ bias1,
                                                 const float* __restrict__ bias2,
                                                 int M, int N, int K) {
  __shared__ u16 As[64][40];
  __shared__ u16 Bs[64][40];
  int nb = N / 64;
  int m0 = (blockIdx.x / nb) * 64;
  int n0 = (blockIdx.x % nb) * 64;
  int tid = threadIdx.x;
  int lane = tid & 63;
  int w = tid >> 6;
  int wm = (w >> 1) * 32, wn = (w & 1) * 32;
  f32x4 acc[2][2] = {};
  int arow = tid >> 2, achk = (tid & 3) * 8;
  for (int k0 = 0; k0 < K; k0 += 32) {
    __syncthreads();
    *(uint4*)&As[arow][achk] = *(const uint4*)&A[(size_t)(m0 + arow) * K + k0 + achk];
    *(uint4*)&Bs[arow][achk] = *(const uint4*)&Bw[(size_t)(n0 + arow) * K + k0 + achk];
    __syncthreads();
    int r = lane & 15, kg = lane >> 4;
    bf16x8 a0 = *(const bf16x8*)&As[wm + r][kg * 8];
    bf16x8 a1 = *(const bf16x8*)&As[wm + 16 + r][kg * 8];
    bf16x8 b0 = *(const bf16x8*)&Bs[wn + r][kg * 8];
    bf16x8 b1 = *(const bf16x8*)&Bs[wn + 16 + r][kg * 8];
    acc[0][0] = __builtin_amdgcn_mfma_f32_16x16x32_bf16(a0, b0, acc[0][0], 0, 0, 0);
    acc[0][1] = __builtin_amdgcn_mfma_f32_16x16x32_bf16(a0, b1, acc[0][1], 0, 0, 0);
    acc[1][0] = __builtin_amdgcn_mfma_f32_16x16x32_bf16(a1, b0, acc[1][0], 0, 0, 0);
    acc[1][1] = __builtin_amdgcn_mfma_f32_16x16x32_bf16(a1, b1, acc[1][1], 0, 0, 0);
  }
  int col = lane & 15, rg = lane >> 4;
#pragma unroll
  for (int fi = 0; fi < 2; fi++)
#pragma unroll
    for (int fj = 0; fj < 2; fj++)
#pragma unroll
      for (int r = 0; r < 4; r++) {
        int m = m0 + wm + fi * 16 + rg * 4 + r;
        int n = n0 + wn + fj * 16 + col;
        float v = acc[fi][fj][r] + bias1[n];
        if constexpr (MODE == 1) {
          v += bias2[n];
          ((float*)out)[(size_t)m * N + n] = v;
        } else {
          ((u16*)out)[(size_t)m * N + n] = f2bf(v);
        }
      }
}

// ---------------- persistent decoder (512 threads) ----------------
struct DecArgs {
  const u16 *pctx, *ctx, *Whh, *Wcomb, *Uxw, *Wxw;
  const float *xW, *bx, *uatt, *xmask, *ymask, *init_h, *init_c;
  float *h, *c, *h1, *c1, *qsum, *attnum, *attden;
  u8* feat8;
  u32* bar;
};

__global__ __launch_bounds__(512, 1) void decoder_coop(DecArgs A) {
  extern __shared__ char smem[];
  u16* pctx_l = (u16*)smem;
  u16* ctx_l = (u16*)(smem + 51200);
  float* ua_l = (float*)(smem + 102400);
  float* xm_l = (float*)(smem + 106496);
  char* un = smem + 106624;

  const int tid = threadIdx.x;
  const int blk = blockIdx.x;
  const int lane = tid & 63, w = tid >> 6;  // w 0..7
  const int g = w & 3, hv = w >> 2;
  const int r16 = lane & 15, kg = lane >> 4;
  const int bK = blk & 15;
  const int s0 = (blk >> 4) * 25;
  u32* qdone = A.bar;
  u32* cdone = A.bar + 64;
  u32* h2done = A.bar + 128;

  for (int idx = tid; idx < 25 * 128; idx += 512) {
    int i = idx >> 7, c8 = (idx & 127) << 3;
    *(uint4*)&pctx_l[i * 1024 + c8] =
        *(const uint4*)&A.pctx[((size_t)(s0 + i) * NB + bK) * CTXD + c8];
    *(uint4*)&ctx_l[i * 1024 + c8] =
        *(const uint4*)&A.ctx[((size_t)(s0 + i) * NB + bK) * CTXD + c8];
  }
  {
    int c0 = tid * 2;
    ua_l[c0] = A.uatt[c0];
    ua_l[c0 + 1] = A.uatt[c0 + 1];
  }
  if (tid < 25) xm_l[tid] = A.xmask[(s0 + tid) * NB + bK];
  __syncthreads();
  float uav[16];
  {
    const float* ub = &ua_l[lane * 16];
    *(f32x4*)&uav[0] = *(const f32x4*)&ub[0];
    *(f32x4*)&uav[4] = *(const f32x4*)&ub[4];
    *(f32x4*)&uav[8] = *(const f32x4*)&ub[8];
    *(f32x4*)&uav[12] = *(const f32x4*)&ub[12];
  }

  for (int ts = 0; ts < T_LEN; ts++) {
    const int par = ts & 1;
    // ========= phase A: LSTM1 + q partials -> qsum (blocks 0..15) =========
    if (blk < 16) {
      if (tid == 0) waitge(h2done, 32u * (u32)ts);
      __syncthreads();
      u16* Al = (u16*)un;
      float* gbA = (float*)(un + 16640);  // [2][4][16][32]
      u16* h1c1 = (u16*)(un + 33024);
      const float* hs = ts ? A.h : A.init_h;
      const float* cs = ts ? A.c : A.init_c;
      const int j0 = blk * 32;
      const int bb = tid >> 5, jj = tid & 31, nn = j0 + jj;
      float h_old, c_old, xw0, xw1, xw2, xw3;
      {
        int k16 = (tid & 31) << 4;
        const float* src = &hs[bb * 512 + k16];
        const float* xw = &A.xW[(size_t)(ts * NB + bb) * K4H];
        f32x4v v0, v1, v2, v3;
        cldA(src, src + 4, src + 8, src + 12,
             &hs[bb * 512 + nn], &cs[bb * 512 + nn],
             &xw[nn], &xw[512 + nn], &xw[1024 + nn], &xw[1536 + nn],
             v0, v1, v2, v3, h_old, c_old, xw0, xw1, xw2, xw3);
        *(uint4*)&Al[bb * 520 + k16] = pack8v(v0, v1);
        *(uint4*)&Al[bb * 520 + k16 + 8] = pack8v(v2, v3);
      }
      __syncthreads();
      {
        f32x4 acc0 = {}, acc1 = {};
        const size_t row0 = (size_t)(g * 512 + j0 + r16) * 512;
        const size_t row1 = (size_t)(g * 512 + j0 + 16 + r16) * 512;
        const int ksb = hv * 8;
#pragma unroll
        for (int ks = 0; ks < 8; ks++) {
          int kk = (ksb + ks) * 32 + kg * 8;
          bf16x8 a = *(const bf16x8*)&Al[r16 * 520 + kk];
          bf16x8 b0 = *(const bf16x8*)&A.Whh[row0 + kk];
          bf16x8 b1 = *(const bf16x8*)&A.Whh[row1 + kk];
          acc0 = __builtin_amdgcn_mfma_f32_16x16x32_bf16(a, b0, acc0, 0, 0, 0);
          acc1 = __builtin_amdgcn_mfma_f32_16x16x32_bf16(a, b1, acc1, 0, 0, 0);
        }
        float* gb = &gbA[((hv * 4 + g) * 16) * 32];
#pragma unroll
        for (int r = 0; r < 4; r++) {
          gb[(kg * 4 + r) * 32 + r16] = acc0[r];
          gb[(kg * 4 + r) * 32 + 16 + r16] = acc1[r];
        }
      }
      __syncthreads();
      {
#define GBA(hh, gg) gbA[(((hh)*4 + (gg)) * 16 + bb) * 32 + jj]
        float gi = GBA(0, 0) + GBA(1, 0) + xw0;
        float gf = GBA(0, 1) + GBA(1, 1) + xw1;
        float gg2 = GBA(0, 2) + GBA(1, 2) + xw2;
        float go = GBA(0, 3) + GBA(1, 3) + xw3;
#undef GBA
        float ymv = A.ymask[ts * NB + bb];
        float c1v = sigm(gf) * c_old + sigm(gi) * tanh_(gg2);
        float h1v = sigm(go) * tanh_(c1v);
        h1v = ymv * h1v + (1.f - ymv) * h_old;
        c1v = ymv * c1v + (1.f - ymv) * c_old;
        ast(&A.h1[bb * 512 + nn], h1v);
        ast(&A.c1[bb * 512 + nn], c1v);
        h1c1[bb * 72 + jj] = f2bf(h1v);
        h1c1[bb * 72 + 32 + jj] = f2bf(c1v);
      }
      __syncthreads();
      {
        bf16x8 a0 = *(const bf16x8*)&h1c1[r16 * 72 + kg * 8];
        bf16x8 a1 = *(const bf16x8*)&h1c1[r16 * 72 + 32 + kg * 8];
        float* qs = A.qsum + par * 16384;
        for (int nt = w; nt < 64; nt += 8) {
          int n = nt * 16 + r16;
          bf16x8 b0 = *(const bf16x8*)&A.Wcomb[(size_t)n * 1024 + j0 + kg * 8];
          bf16x8 b1 = *(const bf16x8*)&A.Wcomb[(size_t)n * 1024 + 512 + j0 + kg * 8];
          f32x4 acc = {};
          acc = __builtin_amdgcn_mfma_f32_16x16x32_bf16(a0, b0, acc, 0, 0, 0);
          acc = __builtin_amdgcn_mfma_f32_16x16x32_bf16(a1, b1, acc, 0, 0, 0);
#pragma unroll
          for (int r = 0; r < 4; r++)
            atomicAdd(&qs[(kg * 4 + r) * 1024 + nt * 16 + r16], acc[r]);
        }
      }
      __syncthreads();
      if (tid == 0) sig(qdone);
    }
    // ========= phase C: attention (all 256 blocks) =========
    {
      if (tid == 0) waitge(qdone, 16u * (u32)(ts + 1));
      __syncthreads();
      float* q_l = (float*)un;
      float* p_l = (float*)(un + 4096);
      {
        int c0 = tid * 2;
        f32x2v qv2 = cldC(&A.qsum[par * 16384 + bK * 1024 + c0]);
        q_l[c0] = qv2.x;
        q_l[c0 + 1] = qv2.y;
      }
      __syncthreads();
      float qv[16];
      {
        const float* qb2 = &q_l[lane * 16];
        *(f32x4*)&qv[0] = *(const f32x4*)&qb2[0];
        *(f32x4*)&qv[4] = *(const f32x4*)&qb2[4];
        *(f32x4*)&qv[8] = *(const f32x4*)&qb2[8];
        *(f32x4*)&qv[12] = *(const f32x4*)&qb2[12];
      }
      for (int i = w; i < 25; i += 8) {
        const u16* prow = &pctx_l[i * 1024 + lane * 16];
        bf16x8 pv0 = *(const bf16x8*)&prow[0];
        bf16x8 pv1 = *(const bf16x8*)&prow[8];
        float s = 0.f;
#pragma unroll
        for (int e = 0; e < 8; e++) s += tanh_(bf2f((u16)pv0[e]) + qv[e]) * uav[e];
#pragma unroll
        for (int e = 0; e < 8; e++) s += tanh_(bf2f((u16)pv1[e]) + qv[8 + e]) * uav[8 + e];
#pragma unroll
        for (int off = 1; off < 64; off <<= 1) s += __shfl_xor(s, off);
        if (lane == 0) {
          float xm = xm_l[i];
          p_l[i] = __expf(s * xm) * xm;
        }
      }
      __syncthreads();
      const int c2 = tid << 1;
      float n0 = 0, n1 = 0;
#pragma unroll 5
      for (int i = 0; i < 25; i++) {
        float pv = p_l[i];
        u32 ld = *(const u32*)&ctx_l[i * 1024 + c2];
        n0 += pv * bf2f((u16)(ld & 0xffff));
        n1 += pv * bf2f((u16)(ld >> 16));
      }
      float* dst = &A.attnum[par * 16384 + bK * 1024 + c2];
      atomicAdd(dst + 0, n0);
      atomicAdd(dst + 1, n1);
      if (tid == 0) {
        float d = 0.f;
        for (int i = 0; i < 25; i++) d += p_l[i];
        atomicAdd(&A.attden[par * NB + bK], d);
      }
      __syncthreads();
      if (tid == 0) sig(cdone);
    }
    // ========= phase D: gates2 + state update (blocks 0..31) =========
    if (blk < 32) {
      if (tid == 0) waitge(cdone, 256u * (u32)(ts + 1));
      __syncthreads();
      u16* AlD = (u16*)un;
      float* gbD = (float*)(un + 49408);      // [4][16][16]
      float* attden_l = (float*)(un + 53504); // [16]
      if (tid < NB) attden_l[tid] = ald(&A.attden[par * NB + tid]);
      gbD[tid] = 0.f;
      gbD[tid + 512] = 0.f;
      const int j0 = blk * 16;
      const int bb = (tid & 255) >> 4, nn = j0 + (tid & 15);
      float c1v, h1v;
      {
        int b = tid >> 5, k16 = (tid & 31) << 4;
        const float* src = &A.h1[b * 512 + k16];
        const float* base = &A.attnum[par * 16384];
        const int rh = tid >> 8, c4 = (tid & 255) << 2;
        const int r0 = rh * 8;
        f32x4v v0, v1, v2, v3, a0, a1, a2, a3, a4, a5, a6, a7;
        cldD(src, src + 4, src + 8, src + 12,
             base + (r0 + 0) * 1024 + c4, base + (r0 + 1) * 1024 + c4,
             base + (r0 + 2) * 1024 + c4, base + (r0 + 3) * 1024 + c4,
             base + (r0 + 4) * 1024 + c4, base + (r0 + 5) * 1024 + c4,
             base + (r0 + 6) * 1024 + c4, base + (r0 + 7) * 1024 + c4,
             &A.c1[bb * 512 + nn], &A.h1[bb * 512 + nn],
             v0, v1, v2, v3, a0, a1, a2, a3, a4, a5, a6, a7, c1v, h1v);
        *(uint4*)&AlD[b * 1544 + k16] = pack8v(v0, v1);
        *(uint4*)&AlD[b * 1544 + k16 + 8] = pack8v(v2, v3);
        __syncthreads();  // attden_l visible
#define ATT_ST(i, vv)                                                        \
  {                                                                          \
    float rd = 1.f / attden_l[i];                                            \
    uint2 t;                                                                 \
    t.x = pack2(vv.x * rd, vv.y * rd);                                       \
    t.y = pack2(vv.z * rd, vv.w * rd);                                       \
    *(uint2*)&AlD[(i) * 1544 + 512 + c4] = t;                                \
  }
        ATT_ST(r0 + 0, a0) ATT_ST(r0 + 1, a1) ATT_ST(r0 + 2, a2) ATT_ST(r0 + 3, a3)
        ATT_ST(r0 + 4, a4) ATT_ST(r0 + 5, a5) ATT_ST(r0 + 6, a6) ATT_ST(r0 + 7, a7)
#undef ATT_ST
      }
      __syncthreads();
      if (blk < 16 && tid < 256) {
        const u16* arow = &AlD[blk * 1544 + 512];
        int c4 = tid * 4;
        u32 p = pkfp8(bf2f(arow[c4]), bf2f(arow[c4 + 1]), bf2f(arow[c4 + 2]),
                      bf2f(arow[c4 + 3]));
        *(u32*)&A.feat8[(size_t)(ts * NB + blk) * K4H + 512 + c4] = p;
      }
      {
        f32x4 acc = {};
        const size_t rowU = (size_t)(g * 512 + j0 + r16) * 512;
        const size_t rowW = (size_t)(g * 512 + j0 + r16) * 1024;
        if (hv == 0) {
#pragma unroll
          for (int ks = 0; ks < 16; ks++) {
            int kk = ks * 32 + kg * 8;
            bf16x8 a = *(const bf16x8*)&AlD[r16 * 1544 + kk];
            bf16x8 b0 = *(const bf16x8*)&A.Uxw[rowU + kk];
            acc = __builtin_amdgcn_mfma_f32_16x16x32_bf16(a, b0, acc, 0, 0, 0);
          }
#pragma unroll
          for (int ks = 16; ks < 24; ks++) {
            bf16x8 a = *(const bf16x8*)&AlD[r16 * 1544 + ks * 32 + kg * 8];
            bf16x8 b0 = *(const bf16x8*)&A.Wxw[rowW + (ks - 16) * 32 + kg * 8];
            acc = __builtin_amdgcn_mfma_f32_16x16x32_bf16(a, b0, acc, 0, 0, 0);
          }
        } else {
#pragma unroll
          for (int ks = 24; ks < 48; ks++) {
            bf16x8 a = *(const bf16x8*)&AlD[r16 * 1544 + ks * 32 + kg * 8];
            bf16x8 b0 = *(const bf16x8*)&A.Wxw[rowW + (ks - 16) * 32 + kg * 8];
            acc = __builtin_amdgcn_mfma_f32_16x16x32_bf16(a, b0, acc, 0, 0, 0);
          }
        }
#pragma unroll
        for (int r = 0; r < 4; r++)
          atomicAdd(&gbD[(g * 16 + kg * 4 + r) * 16 + r16], acc[r]);
      }
      __syncthreads();
      if (tid < 256) {
        int b = bb, j = tid & 15;
        int n = j0 + j;
        float xi = gbD[(0 * 16 + b) * 16 + j] + A.bx[n];
        float xf = gbD[(1 * 16 + b) * 16 + j] + A.bx[512 + n];
        float xo = gbD[(2 * 16 + b) * 16 + j] + A.bx[1024 + n];
        float xc = gbD[(3 * 16 + b) * 16 + j] + A.bx[1536 + n];
        float ymv = A.ymask[ts * NB + b];
        float c2 = sigm(xf) * c1v + sigm(xi) * tanh_(xc);
        float h2 = sigm(xo) * tanh_(c2);
        c2 = ymv * c2 + (1.f - ymv) * c1v;
        h2 = ymv * h2 + (1.f - ymv) * h1v;
        ast(&A.h[b * 512 + n], h2);
        ast(&A.c[b * 512 + n], c2);
        int p8 = 0;
        p8 = __builtin_amdgcn_cvt_pk_fp8_f32(h2, h2, p8, 0);
        A.feat8[(size_t)(ts * NB + b) * K4H + n] = (u8)(p8 & 0xff);
      }
      ast(&A.attnum[(par ^ 1) * 16384 + blk * 512 + tid], 0.f);
      ast(&A.qsum[par * 16384 + blk * 512 + tid], 0.f);
      if (blk == 0 && tid < NB) ast(&A.attden[(par ^ 1) * NB + tid], 0.f);
      __syncthreads();
      if (tid == 0) sig(h2done);
    }
  }
}

// ---------------- fused vocab GEMM (fp8) + sum(exp) ----------------
__global__ __launch_bounds__(512, 1) void lse_gemm_fp8(const u8* __restrict__ feat8,
                                                       const float* __restrict__ Wp,
                                                       const float* __restrict__ bp,
                                                       float* __restrict__ lse) {
  extern __shared__ char smem[];
  u8* Bl = (u8*)smem;  // [64][2064] fp8
  const int tid = threadIdx.x;
  const int n0 = blockIdx.x * 64;
  for (int n = 0; n < 64; n++) {
    int gn = n0 + n;
    f32x4v f = {0.f, 0.f, 0.f, 0.f};
    if (gn < VOC)
      f = __builtin_nontemporal_load((const f32x4v*)&Wp[(size_t)gn * K4H + tid * 4]);
    *(u32*)&Bl[n * 2064 + tid * 4] = pkfp8(f.x, f.y, f.z, f.w);
  }
  __syncthreads();
  const int w = tid >> 6, lane = tid & 63;
  const int r16 = lane & 15, kg = lane >> 4;
  bool vj[4];
  float bpj[4];
#pragma unroll
  for (int j = 0; j < 4; j++) {
    int nf = n0 + j * 16 + r16;
    vj[j] = nf < VOC;
    bpj[j] = vj[j] ? bp[nf] : 0.f;
  }
  for (int qq = w; qq < 25; qq += 8) {
    int mrow = qq * 64;
    f32x4 acc[4][4] = {};
    for (int ks = 0; ks < 64; ks++) {
      i64 b0 = *(const i64*)&Bl[(r16) * 2064 + ks * 32 + kg * 8];
      i64 b1 = *(const i64*)&Bl[(16 + r16) * 2064 + ks * 32 + kg * 8];
      i64 b2 = *(const i64*)&Bl[(32 + r16) * 2064 + ks * 32 + kg * 8];
      i64 b3 = *(const i64*)&Bl[(48 + r16) * 2064 + ks * 32 + kg * 8];
#pragma unroll
      for (int s = 0; s < 4; s++) {
        i64 a = *(const i64*)&feat8[(size_t)(mrow + s * 16 + r16) * K4H + ks * 32 + kg * 8];
        acc[s][0] = __builtin_amdgcn_mfma_f32_16x16x32_fp8_fp8(a, b0, acc[s][0], 0, 0, 0);
        acc[s][1] = __builtin_amdgcn_mfma_f32_16x16x32_fp8_fp8(a, b1, acc[s][1], 0, 0, 0);
        acc[s][2] = __builtin_amdgcn_mfma_f32_16x16x32_fp8_fp8(a, b2, acc[s][2], 0, 0, 0);
        acc[s][3] = __builtin_amdgcn_mfma_f32_16x16x32_fp8_fp8(a, b3, acc[s][3], 0, 0, 0);
      }
    }
#pragma unroll
    for (int s = 0; s < 4; s++) {
#pragma unroll
      for (int r = 0; r < 4; r++) {
        float e = 0.f;
#pragma unroll
        for (int j = 0; j < 4; j++)
          if (vj[j]) e += __expf(acc[s][j][r] + bpj[j]);
        e += __shfl_xor(e, 1);
        e += __shfl_xor(e, 2);
        e += __shfl_xor(e, 4);
        e += __shfl_xor(e, 8);
        if (r16 == 0) atomicAdd(&lse[mrow + s * 16 + kg * 4 + r], e);
      }
    }
  }
}

// ---------------- target logit ----------------
__global__ __launch_bounds__(256) void target_logit(const u8* __restrict__ feat8,
                                                    const float* __restrict__ Wp,
                                                    const float* __restrict__ bp,
                                                    const int* __restrict__ yidx,
                                                    float* __restrict__ tlog) {
  int gw = (blockIdx.x * 256 + threadIdx.x) >> 6;
  int lane = threadIdx.x & 63;
  if (gw >= M_ALL) return;
  int yi = yidx[gw];
  const float* wrow = Wp + (size_t)yi * K4H;
  const u8* frow = feat8 + (size_t)gw * K4H;
  float s = 0.f;
#pragma unroll
  for (int i = 0; i < 4; i++) {
    int k = i * 512 + lane * 8;
    uint2 fv = *(const uint2*)&frow[k];
    f32x4v w0 = __builtin_nontemporal_load((const f32x4v*)&wrow[k]);
    f32x4v w1 = __builtin_nontemporal_load((const f32x4v*)&wrow[k + 4]);
    s += __builtin_amdgcn_cvt_f32_fp8(fv.x, 0) * w0.x;
    s += __builtin_amdgcn_cvt_f32_fp8(fv.x, 1) * w0.y;
    s += __builtin_amdgcn_cvt_f32_fp8(fv.x, 2) * w0.z;
    s += __builtin_amdgcn_cvt_f32_fp8(fv.x, 3) * w0.w;
    s += __builtin_amdgcn_cvt_f32_fp8(fv.y, 0) * w1.x;
    s += __builtin_amdgcn_cvt_f32_fp8(fv.y, 1) * w1.y;
    s += __builtin_amdgcn_cvt_f32_fp8(fv.y, 2) * w1.z;
    s += __builtin_amdgcn_cvt_f32_fp8(fv.y, 3) * w1.w;
  }
#pragma unroll
  for (int off = 1; off < 64; off <<= 1) s += __shfl_xor(s, off);
  if (lane == 0) tlog[gw] = s + bp[yi];
}

__global__ void finalize(const float* __restrict__ lse, const float* __restrict__ tlog,
                         const float* __restrict__ ymask, float* __restrict__ out) {
  int b = threadIdx.x;
  if (b < NB) {
    float sc = 0.f, sm = 0.f;
    for (int t = 0; t < T_LEN; t++) {
      int m = t * NB + b;
      float ym = ymask[m];
      sc += (logf(lse[m]) - tlog[m]) * ym;
      sm += ym;
    }
    out[b] = sc / sm;
  }
}

// ---------------- host launcher ----------------
extern "C" void kernel_launch(void* const* d_in, const int* in_sizes, int n_in,
                              void* d_out, int out_size, void* d_ws, size_t ws_size,
                              hipStream_t stream) {
  const float* y_emb = (const float*)d_in[0];
  const float* context = (const float*)d_in[1];
  const float* init_h = (const float*)d_in[2];
  const float* init_c = (const float*)d_in[3];
  const float* x_mask = (const float*)d_in[4];
  const float* y_mask = (const float*)d_in[5];
  const int* y_idx = (const int*)d_in[6];
  const float* W_ih = (const float*)d_in[7];
  const float* W_hh = (const float*)d_in[8];
  const float* b_ih = (const float*)d_in[9];
  const float* b_hh = (const float*)d_in[10];
  const float* Wx = (const float*)d_in[11];
  const float* Ux = (const float*)d_in[12];
  const float* bx = (const float*)d_in[13];
  const float* Wc_att = (const float*)d_in[14];
  const float* b_att = (const float*)d_in[15];
  const float* W_comb = (const float*)d_in[16];
  const float* U_att = (const float*)d_in[17];
  const float* Wp = (const float*)d_in[18];
  const float* bp = (const float*)d_in[19];

  if (ws_size < 60000000ULL) {
    sentinel_kernel<<<1, 64, 0, stream>>>((float*)d_out, (float)(ws_size >> 20));
    return;
  }

  char* ws = (char*)d_ws;
  float* lse = (float*)(ws + 0);
  float* attnum = (float*)(ws + 8192);
  float* attden = (float*)(ws + 139264);
  u32* bar = (u32*)(ws + 139392);
  float* qsum = (float*)(ws + 151680);
  float* tlog = (float*)(ws + 282752);
  u16* pctx = (u16*)(ws + 294912);
  u16* ctxb = (u16*)(ws + 13402112);
  u16* Wcb = (u16*)(ws + 26509312);
  u16* yembb = (u16*)(ws + 28606464);
  u16* Wihb = (u16*)(ws + 30244864);
  u16* Whhb = (u16*)(ws + 32342016);
  u16* Wcombb = (u16*)(ws + 34439168);
  u16* Uxb = (u16*)(ws + 36536320);
  u16* Wxb = (u16*)(ws + 38633472);
  float* xW = (float*)(ws + 42827776);
  u8* feat8 = (u8*)(ws + 55934976);
  float* hbuf = (float*)(ws + 59211776);
  float* cbuf = (float*)(ws + 59244544);
  float* h1buf = (float*)(ws + 59277312);
  float* c1buf = (float*)(ws + 59310080);

  hipMemsetAsync(ws, 0, 282752, stream);

  CastArgs ca;
  ca.src[0] = context;  ca.dst[0] = ctxb;
  ca.src[1] = Wc_att;   ca.dst[1] = Wcb;
  ca.src[2] = y_emb;    ca.dst[2] = yembb;
  ca.src[3] = W_ih;     ca.dst[3] = Wihb;
  ca.src[4] = W_hh;     ca.dst[4] = Whhb;
  ca.src[5] = W_comb;   ca.dst[5] = Wcombb;
  ca.src[6] = Ux;       ca.dst[6] = Uxb;
  ca.src[7] = Wx;       ca.dst[7] = Wxb;
  ca.src[8] = y_emb;    ca.dst[8] = (u16*)feat8;
  u32 sz[9] = {819200, 131072, 102400, 131072, 131072, 131072, 131072, 262144, 102400};
  ca.cum[0] = 0;
  for (int i = 0; i < 9; i++) ca.cum[i + 1] = ca.cum[i] + sz[i];
  cast_all<<<(ca.cum[9] + 255) / 256, 256, 0, stream>>>(ca);

  gemm_bf16<0><<<1600, 256, 0, stream>>>(ctxb, Wcb, pctx, b_att, b_att, 6400, 1024, 1024);
  gemm_bf16<1><<<800, 256, 0, stream>>>(yembb, Wihb, xW, b_ih, b_hh, 1600, 2048, 512);

  DecArgs a;
  a.pctx = pctx; a.ctx = ctxb; a.Whh = Whhb; a.Wcomb = Wcombb; a.Uxw = Uxb; a.Wxw = Wxb;
  a.xW = xW; a.bx = bx; a.uatt = U_att; a.xmask = x_mask; a.ymask = y_mask;
  a.init_h = init_h; a.init_c = init_c;
  a.h = hbuf; a.c = cbuf; a.h1 = h1buf; a.c1 = c1buf; a.qsum = qsum;
  a.attnum = attnum; a.attden = attden; a.feat8 = feat8; a.bar = bar;
  hipFuncSetAttribute(reinterpret_cast<const void*>(decoder_coop),
                      hipFuncAttributeMaxDynamicSharedMemorySize, 160448);
  decoder_coop<<<256, 512, 160448, stream>>>(a);

  hipFuncSetAttribute(reinterpret_cast<const void*>(lse_gemm_fp8),
                      hipFuncAttributeMaxDynamicSharedMemorySize, 132096);
  lse_gemm_fp8<<<782, 512, 132096, stream>>>(feat8, Wp, bp, lse);

  target_logit<<<400, 256, 0, stream>>>(feat8, Wp, bp, y_idx, tlog);
  finalize<<<1, 64, 0, stream>>>(lse, tlog, y_mask, (float*)d_out);
}